// Round 8
// baseline (605.723 us; speedup 1.0000x reference)
//
#include <hip/hip_runtime.h>
#include <hip/hip_fp16.h>

#define N1 131072
#define E1 2097152
#define N2 2368
#define E2 37888
#define NROIS 148
#define BSZ 16
#define HID 64
#define INCH 128
#define NSEG (BSZ*NROIS)      /* 2368 */
#define SDIM (NROIS*HID)      /* 9472 */
#define CLS 1000
#define OCH 2

#define KT1 148               /* k tiles for k_cls */
#define KCC 64                /* k per tile (148*64 = 9472) */
#define CT1 4                 /* col tiles of 256 */
#define SLP 20                /* LDS slab row stride (floats): 80 B, 16B-aligned */

#define NB1 512               /* dst buckets for graph-1 partition */
#define BLK1 512              /* partition blocks */
#define EPB (E1/BLK1)         /* 4096 edges per block */
#define NPB (N1/NB1)          /* 256 nodes per bucket */
#define P3CAP 5120            /* LDS edge stage cap (mean 4096, sd 64: +16 sd) */

#define CW1 ((N1+15)/16)      /* 8192 conv blocks graph1 (16 nodes/block) */
#define CW2 ((N2+15)/16)      /* 148 conv blocks graph2 */
#define PW  ((NSEG+15)/16)    /* 148 pool blocks per graph */

#define T1 (N1/16)            /* 8192 mfma row-tiles graph1 */
#define T2 (N2/16)            /* 148 mfma row-tiles graph2 */
#define GEMMB ((T1+T2)/4)     /* 2085 gemm blocks (1 tile/wave, 4 waves/block) */

typedef _Float16 h8 __attribute__((ext_vector_type(8)));
typedef float f4 __attribute__((ext_vector_type(4)));

__device__ __forceinline__ unsigned packh2(float a, float b) {
    return (unsigned)__half_as_ushort(__float2half_rn(a)) |
           ((unsigned)__half_as_ushort(__float2half_rn(b)) << 16);
}

// fp32 acc += (f16 half of hb) * w  -- single VALU op, no unpack
__device__ __forceinline__ void fma_lo(float& a, unsigned hb, float w) {
    asm("v_fma_mix_f32 %0, %1, %2, %0 op_sel:[0,0,0] op_sel_hi:[1,0,0]"
        : "+v"(a) : "v"(hb), "v"(w));
}
__device__ __forceinline__ void fma_hi(float& a, unsigned hb, float w) {
    asm("v_fma_mix_f32 %0, %1, %2, %0 op_sel:[1,0,0] op_sel_hi:[1,0,0]"
        : "+v"(a) : "v"(hb), "v"(w));
}

// ---------------- generic small-graph CSR build ----------------

__global__ void k_hist_dst(int* __restrict__ cnt, const int* __restrict__ dst, int E) {
    int e = blockIdx.x * 256 + threadIdx.x;
    if (e < E) atomicAdd(&cnt[dst[e]], 1);
}

__global__ void k_hist_seg2(int* __restrict__ c1, const int* __restrict__ b1,
                            const int* __restrict__ l1, int n1_,
                            int* __restrict__ c2, const int* __restrict__ b2,
                            const int* __restrict__ l2, int n2_) {
    int i = blockIdx.x * 256 + threadIdx.x;
    if (i < n1_) { atomicAdd(&c1[b1[i] * NROIS + l1[i]], 1); return; }
    int j = i - n1_;
    if (j < n2_) atomicAdd(&c2[b2[j] * NROIS + l2[j]], 1);
}

// multi-block exclusive scan (used for the obh bucket histogram)
__global__ void k_scan1(const int* __restrict__ in, int* __restrict__ out,
                        int* __restrict__ part, int n) {
    __shared__ int sh[256];
    int t = threadIdx.x;
    int i0 = blockIdx.x * 1024 + t * 4;
    int v0 = (i0     < n) ? in[i0]     : 0;
    int v1 = (i0 + 1 < n) ? in[i0 + 1] : 0;
    int v2 = (i0 + 2 < n) ? in[i0 + 2] : 0;
    int v3 = (i0 + 3 < n) ? in[i0 + 3] : 0;
    int tot = v0 + v1 + v2 + v3;
    sh[t] = tot; __syncthreads();
    for (int off = 1; off < 256; off <<= 1) {
        int x = 0; if (t >= off) x = sh[t - off];
        __syncthreads();
        if (t >= off) sh[t] += x;
        __syncthreads();
    }
    int excl = sh[t] - tot;
    if (t == 255) part[blockIdx.x] = sh[255];
    if (i0     < n) out[i0]     = excl;
    if (i0 + 1 < n) out[i0 + 1] = excl + v0;
    if (i0 + 2 < n) out[i0 + 2] = excl + v0 + v1;
    if (i0 + 3 < n) out[i0 + 3] = excl + v0 + v1 + v2;
}

__global__ void k_scan2(int* __restrict__ part, int cnt) {
    __shared__ int sh[256];
    int t = threadIdx.x;
    int v = (t < cnt) ? part[t] : 0;
    sh[t] = v; __syncthreads();
    for (int off = 1; off < 256; off <<= 1) {
        int x = 0; if (t >= off) x = sh[t - off];
        __syncthreads();
        if (t >= off) sh[t] += x;
        __syncthreads();
    }
    if (t < cnt) part[t] = sh[t] - v;
}

__global__ void k_scan3(int* __restrict__ out, const int* __restrict__ part, int n, int total) {
    int i = blockIdx.x * 256 + threadIdx.x;
    if (i < n) out[i] += part[i >> 10];
    if (i == 0) out[n] = total;
}

// single-block exclusive scan; block 0 scans set A, block 1 (if in1 != null) set B.
__global__ void k_scan_one(const int* __restrict__ in0, int* __restrict__ out0,
                           int* __restrict__ oo0, int n0,
                           const int* __restrict__ in1, int* __restrict__ out1,
                           int* __restrict__ oo1, int n1_) {
    __shared__ int sh[256];
    __shared__ int carry;
    const int* in; int* out; int* oo; int n;
    if (blockIdx.x == 0) { in = in0; out = out0; oo = oo0; n = n0; }
    else { if (!in1) return; in = in1; out = out1; oo = oo1; n = n1_; }
    int t = threadIdx.x;
    if (t == 0) carry = 0;
    __syncthreads();
    for (int base = 0; base < n; base += 256) {
        int i = base + t;
        int v = (i < n) ? in[i] : 0;
        sh[t] = v; __syncthreads();
        for (int off = 1; off < 256; off <<= 1) {
            int x = 0; if (t >= off) x = sh[t - off];
            __syncthreads();
            if (t >= off) sh[t] += x;
            __syncthreads();
        }
        if (i < n) {
            int e = carry + sh[t] - v;
            out[i] = e;
            if (oo) oo[i] = e;
        }
        __syncthreads();
        if (t == 255) carry += sh[255];
        __syncthreads();
    }
    if (t == 0) out[n] = carry;
}

__global__ void k_fill_edges(int2* __restrict__ edges, int* __restrict__ off,
                             const int* __restrict__ src, const int* __restrict__ dst,
                             const float* __restrict__ ew, int E) {
    int e = blockIdx.x * 256 + threadIdx.x;
    if (e >= E) return;
    int pos = atomicAdd(&off[dst[e]], 1);
    edges[pos] = make_int2(src[e], __float_as_int(ew[e]));
}

// writes PRE-SHIFTED node ids (i << 7 = byte offset of fp16 row) for pool gathers
__global__ void k_fill_seg2(int* __restrict__ id1, int* __restrict__ o1,
                            const int* __restrict__ b1, const int* __restrict__ l1, int n1_,
                            int* __restrict__ id2, int* __restrict__ o2,
                            const int* __restrict__ b2, const int* __restrict__ l2, int n2_) {
    int i = blockIdx.x * 256 + threadIdx.x;
    if (i < n1_) {
        int pos = atomicAdd(&o1[b1[i] * NROIS + l1[i]], 1);
        id1[pos] = i << 7;
        return;
    }
    int j = i - n1_;
    if (j < n2_) {
        int pos = atomicAdd(&o2[b2[j] * NROIS + l2[j]], 1);
        id2[pos] = j << 7;
    }
}

__global__ void k_deg_dinv(float* __restrict__ dinv, const int* __restrict__ row,
                           const int2* __restrict__ edges, int n) {
    int d = blockIdx.x * 256 + threadIdx.x;
    if (d >= n) return;
    int a = row[d], b = row[d + 1];
    float s = 1.0f;
    for (int i = a; i < b; i++) s += __int_as_float(edges[i].y);
    dinv[d] = rsqrtf(s);
}

// scales weights AND pre-shifts src index to byte offset (src << 7)
__global__ void k_scale(int2* __restrict__ edges, const int* __restrict__ row,
                        const float* __restrict__ dinv, int n) {
    int d = blockIdx.x * 256 + threadIdx.x;
    if (d >= n) return;
    int a = row[d], b = row[d + 1];
    float dd = dinv[d];
    for (int i = a; i < b; i++) {
        int2 e = edges[i];
        edges[i] = make_int2(e.x << 7,
                             __float_as_int(dinv[e.x] * __int_as_float(e.y) * dd));
    }
}

// ---------------- graph-1 radix-partition CSR build (v3) ----------------
// p1: bucket histogram + per-node weight sums (global float atomics into ws)
// dinv: ws -> rsqrt(1+ws) in place  (breaks the old p3a/p3b dinv dependency)
// p2: LDS-staged counting sort w/ final weights; coalesced tmp writes
// p3: single pass: per-bucket LDS stage, hist+scan -> row1, scatter to
//     contiguous bucket region of edges1

__global__ __launch_bounds__(256) void k_p1(int* __restrict__ bh, const int* __restrict__ dst,
                                            const float* __restrict__ ew, float* __restrict__ ws) {
    __shared__ int cnt[NB1];
    int t = threadIdx.x, blk = blockIdx.x;
    cnt[t] = 0; cnt[t + 256] = 0;
    __syncthreads();
    int base = blk * EPB;
    const int4* d4 = (const int4*)(dst + base);
    const float4* w4 = (const float4*)(ew + base);
    for (int i = t; i < EPB / 4; i += 256) {
        int4 d = d4[i];
        float4 w = w4[i];
        atomicAdd(&cnt[d.x >> 8], 1); unsafeAtomicAdd(&ws[d.x], w.x);
        atomicAdd(&cnt[d.y >> 8], 1); unsafeAtomicAdd(&ws[d.y], w.y);
        atomicAdd(&cnt[d.z >> 8], 1); unsafeAtomicAdd(&ws[d.z], w.z);
        atomicAdd(&cnt[d.w >> 8], 1); unsafeAtomicAdd(&ws[d.w], w.w);
    }
    __syncthreads();
    bh[t * BLK1 + blk] = cnt[t];                  // bucket-major
    bh[(t + 256) * BLK1 + blk] = cnt[t + 256];
}

__global__ void k_dinv(float* __restrict__ dinv, int n) {
    int i = blockIdx.x * 256 + threadIdx.x;
    if (i < n) dinv[i] = rsqrtf(1.f + dinv[i]);
}

// LDS-staged counting sort into bucket-major tmp; computes FINAL edge weight
// (dinv[src]*ew*dinv[dst]) inline; write-out is linear -> coalesced bucket runs.
__global__ __launch_bounds__(256) void k_p2(int2* __restrict__ tmp, const int* __restrict__ obh,
                                            const int* __restrict__ src,
                                            const int* __restrict__ dst,
                                            const float* __restrict__ ew,
                                            const float* __restrict__ dinv) {
    __shared__ int2 stage[EPB];           // 32 KB bucket-sorted edges
    __shared__ unsigned short bkt[EPB];   // 8 KB bucket per slot
    __shared__ int cnt[NB1];
    __shared__ int lofs[NB1];
    __shared__ int gdel[NB1];
    __shared__ int cur[NB1];
    __shared__ int sc[256];
    __shared__ int cbr;
    int t = threadIdx.x, blk = blockIdx.x;
    cnt[t] = 0; cnt[t + 256] = 0;
    __syncthreads();
    int base = blk * EPB;
    const int4* d4 = (const int4*)(dst + base);
    for (int i = t; i < EPB / 4; i += 256) {
        int4 d = d4[i];
        atomicAdd(&cnt[d.x >> 8], 1);
        atomicAdd(&cnt[d.y >> 8], 1);
        atomicAdd(&cnt[d.z >> 8], 1);
        atomicAdd(&cnt[d.w >> 8], 1);
    }
    __syncthreads();
    // exclusive scan of cnt[512] with 256 threads (2 rounds + carry)
    for (int r = 0; r < 2; r++) {
        int v = cnt[r * 256 + t];
        sc[t] = v; __syncthreads();
        for (int off = 1; off < 256; off <<= 1) {
            int x = 0; if (t >= off) x = sc[t - off];
            __syncthreads();
            if (t >= off) sc[t] += x;
            __syncthreads();
        }
        lofs[r * 256 + t] = (r ? cbr : 0) + sc[t] - v;
        if (t == 255 && r == 0) cbr = sc[255];
        __syncthreads();
    }
    for (int b = t; b < NB1; b += 256) {
        int lo = lofs[b];
        cur[b] = lo;
        gdel[b] = obh[b * BLK1 + blk] - lo;
    }
    __syncthreads();
    // insert with final weights (dinv is 512 KB, L2-resident)
    for (int i = t; i < EPB; i += 256) {
        int e = base + i;
        int d = dst[e];
        int s = src[e];
        float w = dinv[s] * ew[e] * dinv[d];
        int b = d >> 8;
        int p = atomicAdd(&cur[b], 1);
        stage[p] = make_int2(s | ((d & 255) << 17), __float_as_int(w));
        bkt[p] = (unsigned short)b;
    }
    __syncthreads();
    // linear write-out: consecutive i -> consecutive addresses per bucket run
    for (int i = t; i < EPB; i += 256)
        tmp[gdel[bkt[i]] + i] = stage[i];
}

// fused within-bucket sort: hist + scan -> row1, scatter to contiguous region.
// Weights already final (from p2); dinv not needed here.
__global__ __launch_bounds__(256) void k_p3(int2* __restrict__ edges, int* __restrict__ row1,
                                            const int2* __restrict__ tmp,
                                            const int* __restrict__ obh) {
    __shared__ int2 stage[P3CAP];         // 40 KB
    __shared__ int h[NPB];
    __shared__ int sc[256];
    __shared__ int cur[NPB];
    int t = threadIdx.x, b = blockIdx.x;
    h[t] = 0;
    __syncthreads();
    int A = obh[b * BLK1];
    int Eend = (b == NB1 - 1) ? E1 : obh[(b + 1) * BLK1];
    int len = Eend - A;
    for (int j = t; j < len; j += 256) {
        int2 ed = tmp[A + j];
        if (j < P3CAP) stage[j] = ed;     // overflow (statistically ~never) re-read below
        atomicAdd(&h[(ed.x >> 17) & 255], 1);
    }
    __syncthreads();
    int cnt_ = h[t];
    sc[t] = cnt_; __syncthreads();
    for (int off = 1; off < 256; off <<= 1) {
        int x = 0; if (t >= off) x = sc[t - off];
        __syncthreads();
        if (t >= off) sc[t] += x;
        __syncthreads();
    }
    int excl = sc[t] - cnt_;
    row1[b * NPB + t] = A + excl;
    cur[t] = excl;
    if (b == NB1 - 1 && t == 255) row1[N1] = E1;
    __syncthreads();
    for (int j = t; j < len; j += 256) {
        int2 ed = (j < P3CAP) ? stage[j] : tmp[A + j];
        int dl = (ed.x >> 17) & 255;
        int s = ed.x & 0x1FFFF;
        int p = atomicAdd(&cur[dl], 1);
        edges[A + p] = make_int2(s << 7, ed.y);   // region-local write (32 KB window)
    }
}

// ---------------- MFMA gemm ----------------
// out[n][64] = x[n][K] @ W[K][64] via v_mfma_f32_16x16x32_f16.

__device__ __forceinline__ void wfrag(uint4* __restrict__ o, const float* __restrict__ W,
                                      int KCH, int idx) {
    int lane = idx & 63;
    int rest = idx >> 6;
    int ch = rest % KCH;
    int ct = rest / KCH;
    int kr = ch * 32 + ((lane >> 4) * 8);
    int col = ct * 16 + (lane & 15);
    const float* wp = W + (size_t)kr * 64 + col;
    o[idx] = make_uint4(packh2(wp[0],   wp[64]),
                        packh2(wp[128], wp[192]),
                        packh2(wp[256], wp[320]),
                        packh2(wp[384], wp[448]));
}

__global__ void k_wprep(uint4* __restrict__ wf1a, const float* __restrict__ W1a,
                        uint4* __restrict__ wf1b, const float* __restrict__ W1b,
                        uint4* __restrict__ wf2a, const float* __restrict__ W2a,
                        uint4* __restrict__ wf2b, const float* __restrict__ W2b) {
    int idx = blockIdx.x * 256 + threadIdx.x;
    if      (idx < 1024) wfrag(wf1a, W1a, 4, idx);
    else if (idx < 1536) wfrag(wf1b, W1b, 2, idx - 1024);
    else if (idx < 2560) wfrag(wf2a, W2a, 4, idx - 1536);
    else if (idx < 3072) wfrag(wf2b, W2b, 2, idx - 2560);
}

__device__ __forceinline__ h8 loadA(const float* p) {
    float4 a = *(const float4*)p;
    float4 b = *(const float4*)(p + 4);
    union { h8 v; __half h[8]; } u;
    u.h[0] = __float2half_rn(a.x); u.h[1] = __float2half_rn(a.y);
    u.h[2] = __float2half_rn(a.z); u.h[3] = __float2half_rn(a.w);
    u.h[4] = __float2half_rn(b.x); u.h[5] = __float2half_rn(b.y);
    u.h[6] = __float2half_rn(b.z); u.h[7] = __float2half_rn(b.w);
    return u.v;
}
__device__ __forceinline__ h8 loadA(const __half* p) {
    union { h8 v; uint4 u; } u;
    u.u = *(const uint4*)p;
    return u.v;
}

template <int K, typename T>
__global__ __launch_bounds__(256) void k_gemm(__half* __restrict__ out1, const T* __restrict__ x1,
                                              const uint4* __restrict__ wfa, int t1,
                                              __half* __restrict__ out2, const T* __restrict__ x2,
                                              const uint4* __restrict__ wfb, int t2) {
    constexpr int KCH = K / 32;
    int wid = blockIdx.x * 4 + (threadIdx.x >> 6);
    int lane = threadIdx.x & 63;
    __half* out; const T* x; const uint4* wf; int row0;
    if (wid < t1) { out = out1; x = x1; wf = wfa; row0 = wid * 16; }
    else {
        int w2 = wid - t1;
        if (w2 >= t2) return;
        out = out2; x = x2; wf = wfb; row0 = w2 * 16;
    }
    int lrow = lane & 15, lg = lane >> 4;

    h8 bf[4][KCH];
#pragma unroll
    for (int ct = 0; ct < 4; ct++)
#pragma unroll
        for (int ch = 0; ch < KCH; ch++) {
            union { h8 v; uint4 u; } u;
            u.u = wf[(ct * KCH + ch) * 64 + lane];
            bf[ct][ch] = u.v;
        }

    const T* xr = x + (size_t)(row0 + lrow) * K + lg * 8;
    h8 af[KCH];
#pragma unroll
    for (int ch = 0; ch < KCH; ch++) af[ch] = loadA(xr + ch * 32);

    f4 acc[4];
#pragma unroll
    for (int ct = 0; ct < 4; ct++) acc[ct] = (f4){0.f, 0.f, 0.f, 0.f};
#pragma unroll
    for (int ch = 0; ch < KCH; ch++)
#pragma unroll
        for (int ct = 0; ct < 4; ct++)
            acc[ct] = __builtin_amdgcn_mfma_f32_16x16x32_f16(af[ch], bf[ct][ch], acc[ct], 0, 0, 0);

#pragma unroll
    for (int ct = 0; ct < 4; ct++)
#pragma unroll
        for (int r = 0; r < 4; r++)
            out[(size_t)(row0 + lg * 4 + r) * 64 + ct * 16 + lrow] = __float2half_rn(acc[ct][r]);
}

// ---------------- conv / pool (4 nodes/wave, 16 lanes/node, uint4 gathers) ----------------
__device__ __forceinline__ void conv_wave(__half* __restrict__ out, const __half* __restrict__ h,
                                          const int2* __restrict__ edges,
                                          const int* __restrict__ row,
                                          const float* __restrict__ dinv,
                                          const float* __restrict__ bias,
                                          int d0, int n, int lane) {
    int g  = lane >> 4;           // node slot 0..3
    int fl = lane & 15;
    int eh = fl >> 3;             // edge half 0/1
    int f8 = fl & 7;              // feature octet: features f8*8 .. f8*8+7
    int d  = d0 + g;
    bool vn = d < n;
    int a = 0, b = 0;
    if (vn) { a = row[d]; b = row[d + 1]; }
    const char* hb = (const char*)h + f8 * 16;
    float acc[8] = {0.f,0.f,0.f,0.f,0.f,0.f,0.f,0.f};

    for (int base = a; base < b; base += 16) {
        int sv = 0, wv = 0;       // zero-pad: w=0 kills invalid contributions
        if (base + fl < b) { int2 e = edges[base + fl]; sv = e.x; wv = e.y; }
        int mm = b - base; if (mm > 16) mm = 16;
        int steps = (mm + 1) >> 1;
        int idx = (g << 4) + eh;
        for (int t = 0; t < steps; t++) {
            int   s = __shfl(sv, idx + (t << 1));
            float w = __int_as_float(__shfl(wv, idx + (t << 1)));
            uint4 hv = *(const uint4*)(hb + (unsigned)s);
            fma_lo(acc[0], hv.x, w); fma_hi(acc[1], hv.x, w);
            fma_lo(acc[2], hv.y, w); fma_hi(acc[3], hv.y, w);
            fma_lo(acc[4], hv.z, w); fma_hi(acc[5], hv.z, w);
            fma_lo(acc[6], hv.w, w); fma_hi(acc[7], hv.w, w);
        }
    }
    float r[8];
#pragma unroll
    for (int f = 0; f < 8; f++) r[f] = acc[f] + __shfl_xor(acc[f], 8);
    if (vn && eh == 0) {
        float di = dinv[d];
        float sl = di * di;
        uint4 hd = *(const uint4*)(hb + ((unsigned)d << 7));
        fma_lo(r[0], hd.x, sl); fma_hi(r[1], hd.x, sl);
        fma_lo(r[2], hd.y, sl); fma_hi(r[3], hd.y, sl);
        fma_lo(r[4], hd.z, sl); fma_hi(r[5], hd.z, sl);
        fma_lo(r[6], hd.w, sl); fma_hi(r[7], hd.w, sl);
        float4 b0 = *(const float4*)(bias + f8 * 8);
        float4 b1 = *(const float4*)(bias + f8 * 8 + 4);
        uint4 ov;
        ov.x = packh2(fmaxf(r[0] + b0.x, 0.f), fmaxf(r[1] + b0.y, 0.f));
        ov.y = packh2(fmaxf(r[2] + b0.z, 0.f), fmaxf(r[3] + b0.w, 0.f));
        ov.z = packh2(fmaxf(r[4] + b1.x, 0.f), fmaxf(r[5] + b1.y, 0.f));
        ov.w = packh2(fmaxf(r[6] + b1.z, 0.f), fmaxf(r[7] + b1.w, 0.f));
        *(uint4*)(out + (size_t)d * HID + f8 * 8) = ov;
    }
}

__global__ __launch_bounds__(256) void k_conv(__half* __restrict__ o1, const __half* __restrict__ h1,
                                              const int2* __restrict__ e1, const int* __restrict__ r1,
                                              const float* __restrict__ dv1, const float* __restrict__ bi1,
                                              int n1_, int nb1_,
                                              __half* __restrict__ o2, const __half* __restrict__ h2,
                                              const int2* __restrict__ e2, const int* __restrict__ r2,
                                              const float* __restrict__ dv2, const float* __restrict__ bi2,
                                              int n2_) {
    int blk = blockIdx.x;
    int lane = threadIdx.x & 63;
    int wv = threadIdx.x >> 6;
    if (blk < nb1_) conv_wave(o1, h1, e1, r1, dv1, bi1, blk * 16 + wv * 4, n1_, lane);
    else            conv_wave(o2, h2, e2, r2, dv2, bi2, (blk - nb1_) * 16 + wv * 4, n2_, lane);
}

// segment-mean pool, same wave structure (weight 1 / 0-masked).
__device__ __forceinline__ void pool_wave(float* __restrict__ emb, const __half* __restrict__ h,
                                          const int* __restrict__ nodeid,
                                          const int* __restrict__ segrow, int s0, int lane) {
    int g  = lane >> 4;
    int fl = lane & 15;
    int eh = fl >> 3;
    int f8 = fl & 7;
    int s  = s0 + g;
    bool vs = s < NSEG;
    int a = 0, b = 0;
    if (vs) { a = segrow[s]; b = segrow[s + 1]; }
    const char* hb = (const char*)h + f8 * 16;
    float acc[8] = {0.f,0.f,0.f,0.f,0.f,0.f,0.f,0.f};

    for (int base = a; base < b; base += 16) {
        int sv = 0, wv = 0;
        if (base + fl < b) { sv = nodeid[base + fl]; wv = 0x3f800000; }
        int mm = b - base; if (mm > 16) mm = 16;
        int steps = (mm + 1) >> 1;
        int idx = (g << 4) + eh;
        for (int t = 0; t < steps; t++) {
            int   q = __shfl(sv, idx + (t << 1));
            float w = __int_as_float(__shfl(wv, idx + (t << 1)));
            uint4 hv = *(const uint4*)(hb + (unsigned)q);
            fma_lo(acc[0], hv.x, w); fma_hi(acc[1], hv.x, w);
            fma_lo(acc[2], hv.y, w); fma_hi(acc[3], hv.y, w);
            fma_lo(acc[4], hv.z, w); fma_hi(acc[5], hv.z, w);
            fma_lo(acc[6], hv.w, w); fma_hi(acc[7], hv.w, w);
        }
    }
    float r[8];
#pragma unroll
    for (int f = 0; f < 8; f++) r[f] = acc[f] + __shfl_xor(acc[f], 8);
    if (vs && eh == 0) {
        float inv = 1.0f / fmaxf((float)(b - a), 1.0f);
        float4 lo = make_float4(r[0] * inv, r[1] * inv, r[2] * inv, r[3] * inv);
        float4 hi = make_float4(r[4] * inv, r[5] * inv, r[6] * inv, r[7] * inv);
        *(float4*)(emb + (size_t)s * HID + f8 * 8)     = lo;
        *(float4*)(emb + (size_t)s * HID + f8 * 8 + 4) = hi;
    }
}

__global__ __launch_bounds__(256) void k_pool(float* __restrict__ em1, const __half* __restrict__ h1,
                                              const int* __restrict__ id1, const int* __restrict__ sr1,
                                              int nbs,
                                              float* __restrict__ em2, const __half* __restrict__ h2,
                                              const int* __restrict__ id2, const int* __restrict__ sr2) {
    int blk = blockIdx.x;
    int lane = threadIdx.x & 63;
    int wv = threadIdx.x >> 6;
    if (blk < nbs) pool_wave(em1, h1, id1, sr1, blk * 16 + wv * 4, lane);
    else           pool_wave(em2, h2, id2, sr2, (blk - nbs) * 16 + wv * 4, lane);
}

// ---------------- classifier ----------------

__global__ __launch_bounds__(256) void k_cls(float* __restrict__ part_,
                                             const float* __restrict__ e1,
                                             const float* __restrict__ e2,
                                             float* __restrict__ esum,
                                             const float* __restrict__ Wm1) {
    __shared__ float sl[KCC * SLP];     // [kk][b], row stride SLP=20 floats
    int tid = threadIdx.x;
    int kt = blockIdx.x >> 2, ct = blockIdx.x & 3;
    int k0 = kt * KCC;
    bool wr = (ct == 0);
    for (int i = tid; i < KCC * 16; i += 256) {
        int kk = i & (KCC - 1), b = i >> 6;        // coalesced over kk
        int idx = b * SDIM + k0 + kk;
        float v = e1[idx] + e2[idx];
        sl[kk * SLP + b] = v;
        if (wr) esum[idx] = v;
    }
    __syncthreads();
    int c = ct * 256 + tid;
    bool active = c < CLS;
    const float* wp = Wm1 + (size_t)k0 * CLS + c;
    float wv[KCC];
#pragma unroll
    for (int kk = 0; kk < KCC; kk++)
        wv[kk] = active ? wp[(size_t)kk * CLS] : 0.f;   // 64 independent loads in flight
    float acc[16];
#pragma unroll
    for (int b = 0; b < 16; b++) acc[b] = 0.f;
#pragma unroll
    for (int kk = 0; kk < KCC; kk++) {
        float w = wv[kk];
        float4 s0 = *(const float4*)(&sl[kk * SLP + 0]);
        float4 s1 = *(const float4*)(&sl[kk * SLP + 4]);
        float4 s2 = *(const float4*)(&sl[kk * SLP + 8]);
        float4 s3 = *(const float4*)(&sl[kk * SLP + 12]);
        acc[0]  += s0.x * w; acc[1]  += s0.y * w; acc[2]  += s0.z * w; acc[3]  += s0.w * w;
        acc[4]  += s1.x * w; acc[5]  += s1.y * w; acc[6]  += s1.z * w; acc[7]  += s1.w * w;
        acc[8]  += s2.x * w; acc[9]  += s2.y * w; acc[10] += s2.z * w; acc[11] += s2.w * w;
        acc[12] += s3.x * w; acc[13] += s3.y * w; acc[14] += s3.z * w; acc[15] += s3.w * w;
    }
    float* pp = part_ + (size_t)(kt * CT1 + ct) * 16 * 256;
#pragma unroll
    for (int b = 0; b < 16; b++) pp[b * 256 + tid] = acc[b];
}

// reduce partials + BatchNorm + LeakyReLU in one pass
__global__ void k_credbn(float* __restrict__ hact, const float* __restrict__ part_,
                         const float* __restrict__ bm1, const float* __restrict__ gamma,
                         const float* __restrict__ beta, const float* __restrict__ mean,
                         const float* __restrict__ var) {
    int idx = blockIdx.x * 256 + threadIdx.x;
    if (idx >= BSZ * CLS) return;
    int b = idx / CLS, c = idx % CLS;
    int ct = c >> 8, cl = c & 255;
    float sum = 0.f;
#pragma unroll 8
    for (int kt = 0; kt < KT1; kt++)
        sum += part_[((size_t)(kt * CT1 + ct) * 16 + b) * 256 + cl];
    float t = sum + bm1[c];
    t = gamma[c] * (t - mean[c]) * rsqrtf(var[c] + 1e-5f) + beta[c];
    hact[idx] = t > 0.f ? t : 0.01f * t;
}

// one block per batch row; 128 partials per output
__global__ void k_out(float* __restrict__ outp, const float* __restrict__ hact,
                      const float* __restrict__ Wm2, const float* __restrict__ bm2) {
    int b = blockIdx.x;
    int tid = threadIdx.x;
    int o = tid & 1, part = tid >> 1;   // 2 outputs x 128 partials
    float acc = (part == 0) ? bm2[o] : 0.f;
    for (int k = part; k < CLS; k += 128) acc += hact[b * CLS + k] * Wm2[k * OCH + o];
    unsafeAtomicAdd(&outp[b * OCH + o], acc);
}

extern "C" void kernel_launch(void* const* d_in, const int* in_sizes, int n_in,
                              void* d_out, int out_size, void* d_ws, size_t ws_size,
                              hipStream_t stream) {
    const float* x1  = (const float*)d_in[0];
    const int*   nl  = (const int*)d_in[1];
    const int*   ei1 = (const int*)d_in[2];
    const float* ew1 = (const float*)d_in[3];
    const int*   ba1 = (const int*)d_in[4];
    const float* x2  = (const float*)d_in[5];
    const int*   rl  = (const int*)d_in[6];
    const int*   ei2 = (const int*)d_in[7];
    const float* ew2 = (const float*)d_in[8];
    const int*   ba2 = (const int*)d_in[9];
    const float* W1a = (const float*)d_in[10];
    const float* b1a = (const float*)d_in[11];
    const float* W1b = (const float*)d_in[12];
    const float* b1b = (const float*)d_in[13];
    const float* W2a = (const float*)d_in[14];
    const float* b2a = (const float*)d_in[15];
    const float* W2b = (const float*)d_in[16];
    const float* b2b = (const float*)d_in[17];
    const float* Wm1 = (const float*)d_in[18];
    const float* bm1 = (const float*)d_in[19];
    const float* gam = (const float*)d_in[20];
    const float* bet = (const float*)d_in[21];
    const float* bmn = (const float*)d_in[22];
    const float* bvr = (const float*)d_in[23];
    const float* Wm2 = (const float*)d_in[24];
    const float* bm2 = (const float*)d_in[25];

    float* out  = (float*)d_out;
    float* emb1 = out + 32;               // embedding        (16 x 9472)
    float* emb2 = emb1 + NSEG * HID;      // embedding_roi
    float* esum = emb2 + NSEG * HID;      // embedding + embedding_roi

    // ---- workspace carve ----
    char* p = (char*)d_ws;
    auto carve = [&](size_t nbytes) { char* q = p; p += (nbytes + 255) & ~(size_t)255; return (void*)q; };
    int*    row1    = (int*)   carve((N1 + 1) * 4);
    int2*   edges1  = (int2*)  carve((size_t)E1 * 8);
    float*  dinv1   = (float*) carve(N1 * 4);                 // ws sums -> dinv (in place)
    __half* A1h     = (__half*)carve((size_t)N1 * HID * 2);   // fp16 h (gemm out)
    __half* B1h     = (__half*)carve((size_t)N1 * HID * 2);   // fp16 conv out
    int*    nodeid1 = (int*)   carve(N1 * 4);
    int*    segrow1 = (int*)   carve((NSEG + 1) * 4);
    int*    segoff  = (int*)   carve(2 * NSEG * 4);           // [0..NSEG) g1, [NSEG..) g2
    int*    bh      = (int*)   carve((NB1 * BLK1 + 1) * 4);
    int*    obh     = (int*)   carve((NB1 * BLK1 + 1) * 4);
    int*    row2    = (int*)   carve((N2 + 1) * 4);
    int*    off2    = (int*)   carve(N2 * 4);
    int2*   edges2  = (int2*)  carve((size_t)E2 * 8);
    float*  dinv2   = (float*) carve(N2 * 4);
    __half* A2h     = (__half*)carve((size_t)N2 * HID * 2);
    __half* B2h     = (__half*)carve((size_t)N2 * HID * 2);
    int*    nodeid2 = (int*)   carve(N2 * 4);
    int*    segrow2 = (int*)   carve((NSEG + 1) * 4);
    int*    part    = (int*)   carve(256 * 4);
    float*  hact    = (float*) carve(BSZ * CLS * 4);
    uint4*  wf1a    = (uint4*) carve(1024 * 16);              // W fragment buffers
    uint4*  wf1b    = (uint4*) carve(512 * 16);
    uint4*  wf2a    = (uint4*) carve(1024 * 16);
    uint4*  wf2b    = (uint4*) carve(512 * 16);
    int*    segoff1 = segoff;
    int*    segoff2 = segoff + NSEG;
    int2*  tmp1 = (int2*)B1h;   // 16.8 MB aliases B1h (16.8 MB): CSR build done
                                // before conv1's first B1h write
    float* clsp = (float*)B1h;  // 9.7 MB partial slabs alias B1h: dead after pool

    const int* src1 = ei1;
    const int* dst1 = ei1 + E1;
    const int* src2 = ei2;
    const int* dst2 = ei2 + E2;

    hipMemsetAsync(d_out, 0, (size_t)out_size * sizeof(float), stream);

    // ---------------- weight fragment prep (independent; overlaps CSR build) ----
    k_wprep<<<12, 256, 0, stream>>>(wf1a, W1a, wf1b, W1b, wf2a, W2a, wf2b, W2b);

    // ---------------- graph 2 CSR (small) ----------------
    hipMemsetAsync(off2, 0, N2 * 4, stream);
    k_hist_dst<<<(E2 + 255) / 256, 256, 0, stream>>>(off2, dst2, E2);
    k_scan_one<<<1, 256, 0, stream>>>(off2, row2, off2, N2, nullptr, nullptr, nullptr, 0);
    k_fill_edges<<<(E2 + 255) / 256, 256, 0, stream>>>(edges2, off2, src2, dst2, ew2, E2);
    k_deg_dinv<<<(N2 + 255) / 256, 256, 0, stream>>>(dinv2, row2, edges2, N2);
    k_scale<<<(N2 + 255) / 256, 256, 0, stream>>>(edges2, row2, dinv2, N2);

    // ---------------- graph 1 CSR: radix-partition build v3 ----------------
    hipMemsetAsync(dinv1, 0, N1 * 4, stream);
    k_p1<<<BLK1, 256, 0, stream>>>(bh, dst1, ew1, dinv1);        // hist + ws atomics
    k_dinv<<<(N1 + 255) / 256, 256, 0, stream>>>(dinv1, N1);     // ws -> rsqrt(1+ws)
    k_scan1<<<(NB1 * BLK1 + 1023) / 1024, 256, 0, stream>>>(bh, obh, part, NB1 * BLK1);
    k_scan2<<<1, 256, 0, stream>>>(part, (NB1 * BLK1 + 1023) / 1024);
    k_scan3<<<(NB1 * BLK1 + 255) / 256, 256, 0, stream>>>(obh, part, NB1 * BLK1, E1);
    k_p2<<<BLK1, 256, 0, stream>>>(tmp1, obh, src1, dst1, ew1, dinv1);  // sorted + weighted
    k_p3<<<NB1, 256, 0, stream>>>(edges1, row1, tmp1, obh);      // node-sorted CSR + row1

    // ---------------- fused dense pipeline (both graphs per dispatch) ----------------
    k_gemm<INCH, float><<<GEMMB, 256, 0, stream>>>(A1h, x1, wf1a, T1, A2h, x2, wf2a, T2);
    k_conv<<<CW1 + CW2, 256, 0, stream>>>(B1h, A1h, edges1, row1, dinv1, b1a, N1, CW1,
                                          B2h, A2h, edges2, row2, dinv2, b2a, N2);
    k_gemm<HID, __half><<<GEMMB, 256, 0, stream>>>(A1h, B1h, wf1b, T1, A2h, B2h, wf2b, T2);
    k_conv<<<CW1 + CW2, 256, 0, stream>>>(B1h, A1h, edges1, row1, dinv1, b1b, N1, CW1,
                                          B2h, A2h, edges2, row2, dinv2, b2b, N2);

    // ---------------- segment CSR + pool (both graphs) ----------------
    hipMemsetAsync(segoff, 0, 2 * NSEG * 4, stream);
    k_hist_seg2<<<(N1 + N2 + 255) / 256, 256, 0, stream>>>(segoff1, ba1, nl, N1,
                                                           segoff2, ba2, rl, N2);
    k_scan_one<<<2, 256, 0, stream>>>(segoff1, segrow1, segoff1, NSEG,
                                      segoff2, segrow2, segoff2, NSEG);
    k_fill_seg2<<<(N1 + N2 + 255) / 256, 256, 0, stream>>>(nodeid1, segoff1, ba1, nl, N1,
                                                           nodeid2, segoff2, ba2, rl, N2);
    k_pool<<<PW + PW, 256, 0, stream>>>(emb1, B1h, nodeid1, segrow1, PW,
                                        emb2, B2h, nodeid2, segrow2);
    // B1h dead from here; clsp aliases it

    // ---------------- classifier ----------------
    k_cls<<<KT1 * CT1, 256, 0, stream>>>(clsp, emb1, emb2, esum, Wm1);
    k_credbn<<<(BSZ * CLS + 255) / 256, 256, 0, stream>>>(hact, clsp, bm1, gam, bet, bmn, bvr);
    k_out<<<BSZ, 256, 0, stream>>>(out, hact, Wm2, bm2);
}

// Round 9
// 493.567 us; speedup vs baseline: 1.2272x; 1.2272x over previous
//
#include <hip/hip_runtime.h>
#include <hip/hip_fp16.h>

#define N1 131072
#define E1 2097152
#define N2 2368
#define E2 37888
#define NROIS 148
#define BSZ 16
#define HID 64
#define INCH 128
#define NSEG (BSZ*NROIS)      /* 2368 */
#define SDIM (NROIS*HID)      /* 9472 */
#define CLS 1000
#define OCH 2

#define KT1 148               /* k tiles for k_cls */
#define KCC 64                /* k per tile (148*64 = 9472) */
#define CT1 4                 /* col tiles of 256 */
#define SLP 20                /* LDS slab row stride (floats): 80 B, 16B-aligned */

#define NB1 512               /* dst buckets for graph-1 partition */
#define BLK1 512              /* partition blocks */
#define EPB (E1/BLK1)         /* 4096 edges per block */
#define NPB (N1/NB1)          /* 256 nodes per bucket */
#define P3CAP 5120            /* LDS edge stage cap (mean 4096, sd 64: +16 sd) */

#define CW1 ((N1+15)/16)      /* 8192 conv blocks graph1 (16 nodes/block) */
#define CW2 ((N2+15)/16)      /* 148 conv blocks graph2 */
#define PW  ((NSEG+15)/16)    /* 148 pool blocks per graph */

#define T1 (N1/16)            /* 8192 mfma row-tiles graph1 */
#define T2 (N2/16)            /* 148 mfma row-tiles graph2 */
#define GEMMB ((T1+T2)/4)     /* 2085 gemm blocks (1 tile/wave, 4 waves/block) */

typedef _Float16 h8 __attribute__((ext_vector_type(8)));
typedef float f4 __attribute__((ext_vector_type(4)));

__device__ __forceinline__ unsigned packh2(float a, float b) {
    return (unsigned)__half_as_ushort(__float2half_rn(a)) |
           ((unsigned)__half_as_ushort(__float2half_rn(b)) << 16);
}

// fp32 acc += (f16 half of hb) * w  -- single VALU op, no unpack
__device__ __forceinline__ void fma_lo(float& a, unsigned hb, float w) {
    asm("v_fma_mix_f32 %0, %1, %2, %0 op_sel:[0,0,0] op_sel_hi:[1,0,0]"
        : "+v"(a) : "v"(hb), "v"(w));
}
__device__ __forceinline__ void fma_hi(float& a, unsigned hb, float w) {
    asm("v_fma_mix_f32 %0, %1, %2, %0 op_sel:[1,0,0] op_sel_hi:[1,0,0]"
        : "+v"(a) : "v"(hb), "v"(w));
}

// ======= dinv factoring (no dinv needed in CSR build) =======
// out[d] = dinv[d]*( sum_s ew*(dinv[s]*h[s]) + dinv[d]*h[d] ) + bias
// gemm1 scales rows by dinv (H~ = dinv*h); conv aggregates RAW ew over H~,
// adds H~[d] (self), multiplies by dinv[d], adds bias, relu. conv1 outputs
// dinv[d]*relu(v) (pre-scaled for the next gemm); conv2 outputs plain.

// ---------------- generic small-graph CSR build ----------------

__global__ void k_hist_dst(int* __restrict__ cnt, const int* __restrict__ dst, int E) {
    int e = blockIdx.x * 256 + threadIdx.x;
    if (e < E) atomicAdd(&cnt[dst[e]], 1);
}

__global__ void k_hist_seg2(int* __restrict__ c1, const int* __restrict__ b1,
                            const int* __restrict__ l1, int n1_,
                            int* __restrict__ c2, const int* __restrict__ b2,
                            const int* __restrict__ l2, int n2_) {
    int i = blockIdx.x * 256 + threadIdx.x;
    if (i < n1_) { atomicAdd(&c1[b1[i] * NROIS + l1[i]], 1); return; }
    int j = i - n1_;
    if (j < n2_) atomicAdd(&c2[b2[j] * NROIS + l2[j]], 1);
}

// multi-block exclusive scan (used for the obh bucket histogram)
__global__ void k_scan1(const int* __restrict__ in, int* __restrict__ out,
                        int* __restrict__ part, int n) {
    __shared__ int sh[256];
    int t = threadIdx.x;
    int i0 = blockIdx.x * 1024 + t * 4;
    int v0 = (i0     < n) ? in[i0]     : 0;
    int v1 = (i0 + 1 < n) ? in[i0 + 1] : 0;
    int v2 = (i0 + 2 < n) ? in[i0 + 2] : 0;
    int v3 = (i0 + 3 < n) ? in[i0 + 3] : 0;
    int tot = v0 + v1 + v2 + v3;
    sh[t] = tot; __syncthreads();
    for (int off = 1; off < 256; off <<= 1) {
        int x = 0; if (t >= off) x = sh[t - off];
        __syncthreads();
        if (t >= off) sh[t] += x;
        __syncthreads();
    }
    int excl = sh[t] - tot;
    if (t == 255) part[blockIdx.x] = sh[255];
    if (i0     < n) out[i0]     = excl;
    if (i0 + 1 < n) out[i0 + 1] = excl + v0;
    if (i0 + 2 < n) out[i0 + 2] = excl + v0 + v1;
    if (i0 + 3 < n) out[i0 + 3] = excl + v0 + v1 + v2;
}

__global__ void k_scan2(int* __restrict__ part, int cnt) {
    __shared__ int sh[256];
    int t = threadIdx.x;
    int v = (t < cnt) ? part[t] : 0;
    sh[t] = v; __syncthreads();
    for (int off = 1; off < 256; off <<= 1) {
        int x = 0; if (t >= off) x = sh[t - off];
        __syncthreads();
        if (t >= off) sh[t] += x;
        __syncthreads();
    }
    if (t < cnt) part[t] = sh[t] - v;
}

__global__ void k_scan3(int* __restrict__ out, const int* __restrict__ part, int n, int total) {
    int i = blockIdx.x * 256 + threadIdx.x;
    if (i < n) out[i] += part[i >> 10];
    if (i == 0) out[n] = total;
}

// single-block exclusive scan; block 0 scans set A, block 1 (if in1 != null) set B.
__global__ void k_scan_one(const int* __restrict__ in0, int* __restrict__ out0,
                           int* __restrict__ oo0, int n0,
                           const int* __restrict__ in1, int* __restrict__ out1,
                           int* __restrict__ oo1, int n1_) {
    __shared__ int sh[256];
    __shared__ int carry;
    const int* in; int* out; int* oo; int n;
    if (blockIdx.x == 0) { in = in0; out = out0; oo = oo0; n = n0; }
    else { if (!in1) return; in = in1; out = out1; oo = oo1; n = n1_; }
    int t = threadIdx.x;
    if (t == 0) carry = 0;
    __syncthreads();
    for (int base = 0; base < n; base += 256) {
        int i = base + t;
        int v = (i < n) ? in[i] : 0;
        sh[t] = v; __syncthreads();
        for (int off = 1; off < 256; off <<= 1) {
            int x = 0; if (t >= off) x = sh[t - off];
            __syncthreads();
            if (t >= off) sh[t] += x;
            __syncthreads();
        }
        if (i < n) {
            int e = carry + sh[t] - v;
            out[i] = e;
            if (oo) oo[i] = e;
        }
        __syncthreads();
        if (t == 255) carry += sh[255];
        __syncthreads();
    }
    if (t == 0) out[n] = carry;
}

// writes PRE-SHIFTED src (byte offset) + RAW weight
__global__ void k_fill_edges(int2* __restrict__ edges, int* __restrict__ off,
                             const int* __restrict__ src, const int* __restrict__ dst,
                             const float* __restrict__ ew, int E) {
    int e = blockIdx.x * 256 + threadIdx.x;
    if (e >= E) return;
    int pos = atomicAdd(&off[dst[e]], 1);
    edges[pos] = make_int2(src[e] << 7, __float_as_int(ew[e]));
}

// writes PRE-SHIFTED node ids (i << 7 = byte offset of fp16 row) for pool gathers
__global__ void k_fill_seg2(int* __restrict__ id1, int* __restrict__ o1,
                            const int* __restrict__ b1, const int* __restrict__ l1, int n1_,
                            int* __restrict__ id2, int* __restrict__ o2,
                            const int* __restrict__ b2, const int* __restrict__ l2, int n2_) {
    int i = blockIdx.x * 256 + threadIdx.x;
    if (i < n1_) {
        int pos = atomicAdd(&o1[b1[i] * NROIS + l1[i]], 1);
        id1[pos] = i << 7;
        return;
    }
    int j = i - n1_;
    if (j < n2_) {
        int pos = atomicAdd(&o2[b2[j] * NROIS + l2[j]], 1);
        id2[pos] = j << 7;
    }
}

__global__ void k_deg_dinv(float* __restrict__ dinv, const int* __restrict__ row,
                           const int2* __restrict__ edges, int n) {
    int d = blockIdx.x * 256 + threadIdx.x;
    if (d >= n) return;
    int a = row[d], b = row[d + 1];
    float s = 1.0f;
    for (int i = a; i < b; i++) s += __int_as_float(edges[i].y);
    dinv[d] = rsqrtf(s);
}

// ---------------- graph-1 radix-partition CSR build (v4) ----------------
// p1: bucket histogram only (vectorized)
// p2: LDS-staged counting sort with RAW weights; coalesced tmp writes
// p3: single pass: per-bucket LDS stage, hist + weight-sum -> row1 + dinv,
//     scatter raw-weight edges to contiguous bucket region

__global__ __launch_bounds__(256) void k_p1(int* __restrict__ bh, const int* __restrict__ dst) {
    __shared__ int cnt[NB1];
    int t = threadIdx.x, blk = blockIdx.x;
    cnt[t] = 0; cnt[t + 256] = 0;
    __syncthreads();
    int base = blk * EPB;
    const int4* d4 = (const int4*)(dst + base);
    for (int i = t; i < EPB / 4; i += 256) {
        int4 d = d4[i];
        atomicAdd(&cnt[d.x >> 8], 1);
        atomicAdd(&cnt[d.y >> 8], 1);
        atomicAdd(&cnt[d.z >> 8], 1);
        atomicAdd(&cnt[d.w >> 8], 1);
    }
    __syncthreads();
    bh[t * BLK1 + blk] = cnt[t];                  // bucket-major
    bh[(t + 256) * BLK1 + blk] = cnt[t + 256];
}

// LDS-staged counting sort into bucket-major tmp with RAW weights;
// write-out is linear -> coalesced bucket runs.
__global__ __launch_bounds__(256) void k_p2(int2* __restrict__ tmp, const int* __restrict__ obh,
                                            const int* __restrict__ src,
                                            const int* __restrict__ dst,
                                            const float* __restrict__ ew) {
    __shared__ int2 stage[EPB];           // 32 KB bucket-sorted edges
    __shared__ unsigned short bkt[EPB];   // 8 KB bucket per slot
    __shared__ int cnt[NB1];
    __shared__ int lofs[NB1];
    __shared__ int gdel[NB1];
    __shared__ int cur[NB1];
    __shared__ int sc[256];
    __shared__ int cbr;
    int t = threadIdx.x, blk = blockIdx.x;
    cnt[t] = 0; cnt[t + 256] = 0;
    __syncthreads();
    int base = blk * EPB;
    const int4* d4 = (const int4*)(dst + base);
    for (int i = t; i < EPB / 4; i += 256) {
        int4 d = d4[i];
        atomicAdd(&cnt[d.x >> 8], 1);
        atomicAdd(&cnt[d.y >> 8], 1);
        atomicAdd(&cnt[d.z >> 8], 1);
        atomicAdd(&cnt[d.w >> 8], 1);
    }
    __syncthreads();
    // exclusive scan of cnt[512] with 256 threads (2 rounds + carry)
    for (int r = 0; r < 2; r++) {
        int v = cnt[r * 256 + t];
        sc[t] = v; __syncthreads();
        for (int off = 1; off < 256; off <<= 1) {
            int x = 0; if (t >= off) x = sc[t - off];
            __syncthreads();
            if (t >= off) sc[t] += x;
            __syncthreads();
        }
        lofs[r * 256 + t] = (r ? cbr : 0) + sc[t] - v;
        if (t == 255 && r == 0) cbr = sc[255];
        __syncthreads();
    }
    for (int b = t; b < NB1; b += 256) {
        int lo = lofs[b];
        cur[b] = lo;
        gdel[b] = obh[b * BLK1 + blk] - lo;
    }
    __syncthreads();
    for (int i = t; i < EPB; i += 256) {
        int e = base + i;
        int d = dst[e];
        int b = d >> 8;
        int p = atomicAdd(&cur[b], 1);
        stage[p] = make_int2(src[e] | ((d & 255) << 17), __float_as_int(ew[e]));
        bkt[p] = (unsigned short)b;
    }
    __syncthreads();
    // linear write-out: consecutive i -> consecutive addresses per bucket run
    for (int i = t; i < EPB; i += 256)
        tmp[gdel[bkt[i]] + i] = stage[i];
}

// fused within-bucket sort + dinv: hist + weight sums + scan -> row1 + dinv1,
// scatter raw-weight edges to contiguous region.
__global__ __launch_bounds__(256) void k_p3(int2* __restrict__ edges, int* __restrict__ row1,
                                            float* __restrict__ dinv1,
                                            const int2* __restrict__ tmp,
                                            const int* __restrict__ obh) {
    __shared__ int2 stage[P3CAP];         // 40 KB
    __shared__ int h[NPB];
    __shared__ float ws[NPB];
    __shared__ int sc[256];
    __shared__ int cur[NPB];
    int t = threadIdx.x, b = blockIdx.x;
    h[t] = 0; ws[t] = 0.f;
    __syncthreads();
    int A = obh[b * BLK1];
    int Eend = (b == NB1 - 1) ? E1 : obh[(b + 1) * BLK1];
    int len = Eend - A;
    for (int j = t; j < len; j += 256) {
        int2 ed = tmp[A + j];
        if (j < P3CAP) stage[j] = ed;     // overflow (statistically ~never) re-read below
        int dl = (ed.x >> 17) & 255;
        atomicAdd(&h[dl], 1);
        atomicAdd(&ws[dl], __int_as_float(ed.y));
    }
    __syncthreads();
    int cnt_ = h[t];
    sc[t] = cnt_; __syncthreads();
    for (int off = 1; off < 256; off <<= 1) {
        int x = 0; if (t >= off) x = sc[t - off];
        __syncthreads();
        if (t >= off) sc[t] += x;
        __syncthreads();
    }
    int excl = sc[t] - cnt_;
    row1[b * NPB + t] = A + excl;
    dinv1[b * NPB + t] = rsqrtf(1.f + ws[t]);
    cur[t] = excl;
    if (b == NB1 - 1 && t == 255) row1[N1] = E1;
    __syncthreads();
    for (int j = t; j < len; j += 256) {
        int2 ed = (j < P3CAP) ? stage[j] : tmp[A + j];
        int dl = (ed.x >> 17) & 255;
        int s = ed.x & 0x1FFFF;
        int p = atomicAdd(&cur[dl], 1);
        edges[A + p] = make_int2(s << 7, ed.y);   // raw weight; region-local write
    }
}

// ---------------- MFMA gemm ----------------
// out[n][64] = x[n][K] @ W[K][64] via v_mfma_f32_16x16x32_f16.
// Optional dv: scale output row r by dv[r] (H~ = dinv * h).

__device__ __forceinline__ void wfrag(uint4* __restrict__ o, const float* __restrict__ W,
                                      int KCH, int idx) {
    int lane = idx & 63;
    int rest = idx >> 6;
    int ch = rest % KCH;
    int ct = rest / KCH;
    int kr = ch * 32 + ((lane >> 4) * 8);
    int col = ct * 16 + (lane & 15);
    const float* wp = W + (size_t)kr * 64 + col;
    o[idx] = make_uint4(packh2(wp[0],   wp[64]),
                        packh2(wp[128], wp[192]),
                        packh2(wp[256], wp[320]),
                        packh2(wp[384], wp[448]));
}

__global__ void k_wprep(uint4* __restrict__ wf1a, const float* __restrict__ W1a,
                        uint4* __restrict__ wf1b, const float* __restrict__ W1b,
                        uint4* __restrict__ wf2a, const float* __restrict__ W2a,
                        uint4* __restrict__ wf2b, const float* __restrict__ W2b) {
    int idx = blockIdx.x * 256 + threadIdx.x;
    if      (idx < 1024) wfrag(wf1a, W1a, 4, idx);
    else if (idx < 1536) wfrag(wf1b, W1b, 2, idx - 1024);
    else if (idx < 2560) wfrag(wf2a, W2a, 4, idx - 1536);
    else if (idx < 3072) wfrag(wf2b, W2b, 2, idx - 2560);
}

__device__ __forceinline__ h8 loadA(const float* p) {
    float4 a = *(const float4*)p;
    float4 b = *(const float4*)(p + 4);
    union { h8 v; __half h[8]; } u;
    u.h[0] = __float2half_rn(a.x); u.h[1] = __float2half_rn(a.y);
    u.h[2] = __float2half_rn(a.z); u.h[3] = __float2half_rn(a.w);
    u.h[4] = __float2half_rn(b.x); u.h[5] = __float2half_rn(b.y);
    u.h[6] = __float2half_rn(b.z); u.h[7] = __float2half_rn(b.w);
    return u.v;
}
__device__ __forceinline__ h8 loadA(const __half* p) {
    union { h8 v; uint4 u; } u;
    u.u = *(const uint4*)p;
    return u.v;
}

template <int K, typename T>
__global__ __launch_bounds__(256) void k_gemm(__half* __restrict__ out1, const T* __restrict__ x1,
                                              const uint4* __restrict__ wfa,
                                              const float* __restrict__ dva, int t1,
                                              __half* __restrict__ out2, const T* __restrict__ x2,
                                              const uint4* __restrict__ wfb,
                                              const float* __restrict__ dvb, int t2) {
    constexpr int KCH = K / 32;
    int wid = blockIdx.x * 4 + (threadIdx.x >> 6);
    int lane = threadIdx.x & 63;
    __half* out; const T* x; const uint4* wf; const float* dv; int row0;
    if (wid < t1) { out = out1; x = x1; wf = wfa; dv = dva; row0 = wid * 16; }
    else {
        int w2 = wid - t1;
        if (w2 >= t2) return;
        out = out2; x = x2; wf = wfb; dv = dvb; row0 = w2 * 16;
    }
    int lrow = lane & 15, lg = lane >> 4;

    h8 bf[4][KCH];
#pragma unroll
    for (int ct = 0; ct < 4; ct++)
#pragma unroll
        for (int ch = 0; ch < KCH; ch++) {
            union { h8 v; uint4 u; } u;
            u.u = wf[(ct * KCH + ch) * 64 + lane];
            bf[ct][ch] = u.v;
        }

    const T* xr = x + (size_t)(row0 + lrow) * K + lg * 8;
    h8 af[KCH];
#pragma unroll
    for (int ch = 0; ch < KCH; ch++) af[ch] = loadA(xr + ch * 32);

    f4 acc[4];
#pragma unroll
    for (int ct = 0; ct < 4; ct++) acc[ct] = (f4){0.f, 0.f, 0.f, 0.f};
#pragma unroll
    for (int ch = 0; ch < KCH; ch++)
#pragma unroll
        for (int ct = 0; ct < 4; ct++)
            acc[ct] = __builtin_amdgcn_mfma_f32_16x16x32_f16(af[ch], bf[ct][ch], acc[ct], 0, 0, 0);

    float scs[4] = {1.f, 1.f, 1.f, 1.f};
    if (dv) {
#pragma unroll
        for (int r = 0; r < 4; r++) scs[r] = dv[row0 + lg * 4 + r];
    }
#pragma unroll
    for (int ct = 0; ct < 4; ct++)
#pragma unroll
        for (int r = 0; r < 4; r++)
            out[(size_t)(row0 + lg * 4 + r) * 64 + ct * 16 + lrow] =
                __float2half_rn(acc[ct][r] * scs[r]);
}

// ---------------- conv / pool (4 nodes/wave, 16 lanes/node, uint4 gathers) ----------------
// Aggregates RAW ew over pre-scaled features H~; epilogue:
//   v = dinv[d]*(sum + H~[d]) + bias; out = relu(v) * (presc ? dinv[d] : 1)
__device__ __forceinline__ void conv_wave(__half* __restrict__ out, const __half* __restrict__ h,
                                          const int2* __restrict__ edges,
                                          const int* __restrict__ row,
                                          const float* __restrict__ dinv,
                                          const float* __restrict__ bias,
                                          int d0, int n, int lane, int presc) {
    int g  = lane >> 4;           // node slot 0..3
    int fl = lane & 15;
    int eh = fl >> 3;             // edge half 0/1
    int f8 = fl & 7;              // feature octet: features f8*8 .. f8*8+7
    int d  = d0 + g;
    bool vn = d < n;
    int a = 0, b = 0;
    if (vn) { a = row[d]; b = row[d + 1]; }
    const char* hb = (const char*)h + f8 * 16;
    float acc[8] = {0.f,0.f,0.f,0.f,0.f,0.f,0.f,0.f};

    for (int base = a; base < b; base += 16) {
        int sv = 0, wv = 0;       // zero-pad: w=0 kills invalid contributions
        if (base + fl < b) { int2 e = edges[base + fl]; sv = e.x; wv = e.y; }
        int mm = b - base; if (mm > 16) mm = 16;
        int steps = (mm + 1) >> 1;
        int idx = (g << 4) + eh;
        for (int t = 0; t < steps; t++) {
            int   s = __shfl(sv, idx + (t << 1));
            float w = __int_as_float(__shfl(wv, idx + (t << 1)));
            uint4 hv = *(const uint4*)(hb + (unsigned)s);
            fma_lo(acc[0], hv.x, w); fma_hi(acc[1], hv.x, w);
            fma_lo(acc[2], hv.y, w); fma_hi(acc[3], hv.y, w);
            fma_lo(acc[4], hv.z, w); fma_hi(acc[5], hv.z, w);
            fma_lo(acc[6], hv.w, w); fma_hi(acc[7], hv.w, w);
        }
    }
    float r[8];
#pragma unroll
    for (int f = 0; f < 8; f++) r[f] = acc[f] + __shfl_xor(acc[f], 8);
    if (vn && eh == 0) {
        float di = dinv[d];
        uint4 hd = *(const uint4*)(hb + ((unsigned)d << 7));
        fma_lo(r[0], hd.x, 1.f); fma_hi(r[1], hd.x, 1.f);
        fma_lo(r[2], hd.y, 1.f); fma_hi(r[3], hd.y, 1.f);
        fma_lo(r[4], hd.z, 1.f); fma_hi(r[5], hd.z, 1.f);
        fma_lo(r[6], hd.w, 1.f); fma_hi(r[7], hd.w, 1.f);
        float4 b0 = *(const float4*)(bias + f8 * 8);
        float4 b1 = *(const float4*)(bias + f8 * 8 + 4);
        float osc = presc ? di : 1.f;
        float o0 = fmaxf(di * r[0] + b0.x, 0.f) * osc;
        float o1 = fmaxf(di * r[1] + b0.y, 0.f) * osc;
        float o2 = fmaxf(di * r[2] + b0.z, 0.f) * osc;
        float o3 = fmaxf(di * r[3] + b0.w, 0.f) * osc;
        float o4 = fmaxf(di * r[4] + b1.x, 0.f) * osc;
        float o5 = fmaxf(di * r[5] + b1.y, 0.f) * osc;
        float o6 = fmaxf(di * r[6] + b1.z, 0.f) * osc;
        float o7 = fmaxf(di * r[7] + b1.w, 0.f) * osc;
        uint4 ov;
        ov.x = packh2(o0, o1);
        ov.y = packh2(o2, o3);
        ov.z = packh2(o4, o5);
        ov.w = packh2(o6, o7);
        *(uint4*)(out + (size_t)d * HID + f8 * 8) = ov;
    }
}

__global__ __launch_bounds__(256) void k_conv(__half* __restrict__ o1, const __half* __restrict__ h1,
                                              const int2* __restrict__ e1, const int* __restrict__ r1,
                                              const float* __restrict__ dv1, const float* __restrict__ bi1,
                                              int n1_, int nb1_,
                                              __half* __restrict__ o2, const __half* __restrict__ h2,
                                              const int2* __restrict__ e2, const int* __restrict__ r2,
                                              const float* __restrict__ dv2, const float* __restrict__ bi2,
                                              int n2_, int presc) {
    int blk = blockIdx.x;
    int lane = threadIdx.x & 63;
    int wv = threadIdx.x >> 6;
    if (blk < nb1_) conv_wave(o1, h1, e1, r1, dv1, bi1, blk * 16 + wv * 4, n1_, lane, presc);
    else            conv_wave(o2, h2, e2, r2, dv2, bi2, (blk - nb1_) * 16 + wv * 4, n2_, lane, presc);
}

// segment-mean pool, same wave structure (weight 1 / 0-masked).
__device__ __forceinline__ void pool_wave(float* __restrict__ emb, const __half* __restrict__ h,
                                          const int* __restrict__ nodeid,
                                          const int* __restrict__ segrow, int s0, int lane) {
    int g  = lane >> 4;
    int fl = lane & 15;
    int eh = fl >> 3;
    int f8 = fl & 7;
    int s  = s0 + g;
    bool vs = s < NSEG;
    int a = 0, b = 0;
    if (vs) { a = segrow[s]; b = segrow[s + 1]; }
    const char* hb = (const char*)h + f8 * 16;
    float acc[8] = {0.f,0.f,0.f,0.f,0.f,0.f,0.f,0.f};

    for (int base = a; base < b; base += 16) {
        int sv = 0, wv = 0;
        if (base + fl < b) { sv = nodeid[base + fl]; wv = 0x3f800000; }
        int mm = b - base; if (mm > 16) mm = 16;
        int steps = (mm + 1) >> 1;
        int idx = (g << 4) + eh;
        for (int t = 0; t < steps; t++) {
            int   q = __shfl(sv, idx + (t << 1));
            float w = __int_as_float(__shfl(wv, idx + (t << 1)));
            uint4 hv = *(const uint4*)(hb + (unsigned)q);
            fma_lo(acc[0], hv.x, w); fma_hi(acc[1], hv.x, w);
            fma_lo(acc[2], hv.y, w); fma_hi(acc[3], hv.y, w);
            fma_lo(acc[4], hv.z, w); fma_hi(acc[5], hv.z, w);
            fma_lo(acc[6], hv.w, w); fma_hi(acc[7], hv.w, w);
        }
    }
    float r[8];
#pragma unroll
    for (int f = 0; f < 8; f++) r[f] = acc[f] + __shfl_xor(acc[f], 8);
    if (vs && eh == 0) {
        float inv = 1.0f / fmaxf((float)(b - a), 1.0f);
        float4 lo = make_float4(r[0] * inv, r[1] * inv, r[2] * inv, r[3] * inv);
        float4 hi = make_float4(r[4] * inv, r[5] * inv, r[6] * inv, r[7] * inv);
        *(float4*)(emb + (size_t)s * HID + f8 * 8)     = lo;
        *(float4*)(emb + (size_t)s * HID + f8 * 8 + 4) = hi;
    }
}

__global__ __launch_bounds__(256) void k_pool(float* __restrict__ em1, const __half* __restrict__ h1,
                                              const int* __restrict__ id1, const int* __restrict__ sr1,
                                              int nbs,
                                              float* __restrict__ em2, const __half* __restrict__ h2,
                                              const int* __restrict__ id2, const int* __restrict__ sr2) {
    int blk = blockIdx.x;
    int lane = threadIdx.x & 63;
    int wv = threadIdx.x >> 6;
    if (blk < nbs) pool_wave(em1, h1, id1, sr1, blk * 16 + wv * 4, lane);
    else           pool_wave(em2, h2, id2, sr2, (blk - nbs) * 16 + wv * 4, lane);
}

// ---------------- classifier ----------------

__global__ __launch_bounds__(256) void k_cls(float* __restrict__ part_,
                                             const float* __restrict__ e1,
                                             const float* __restrict__ e2,
                                             float* __restrict__ esum,
                                             const float* __restrict__ Wm1) {
    __shared__ float sl[KCC * SLP];     // [kk][b], row stride SLP=20 floats
    int tid = threadIdx.x;
    int kt = blockIdx.x >> 2, ct = blockIdx.x & 3;
    int k0 = kt * KCC;
    bool wr = (ct == 0);
    for (int i = tid; i < KCC * 16; i += 256) {
        int kk = i & (KCC - 1), b = i >> 6;        // coalesced over kk
        int idx = b * SDIM + k0 + kk;
        float v = e1[idx] + e2[idx];
        sl[kk * SLP + b] = v;
        if (wr) esum[idx] = v;
    }
    __syncthreads();
    int c = ct * 256 + tid;
    bool active = c < CLS;
    const float* wp = Wm1 + (size_t)k0 * CLS + c;
    float wv[KCC];
#pragma unroll
    for (int kk = 0; kk < KCC; kk++)
        wv[kk] = active ? wp[(size_t)kk * CLS] : 0.f;   // 64 independent loads in flight
    float acc[16];
#pragma unroll
    for (int b = 0; b < 16; b++) acc[b] = 0.f;
#pragma unroll
    for (int kk = 0; kk < KCC; kk++) {
        float w = wv[kk];
        float4 s0 = *(const float4*)(&sl[kk * SLP + 0]);
        float4 s1 = *(const float4*)(&sl[kk * SLP + 4]);
        float4 s2 = *(const float4*)(&sl[kk * SLP + 8]);
        float4 s3 = *(const float4*)(&sl[kk * SLP + 12]);
        acc[0]  += s0.x * w; acc[1]  += s0.y * w; acc[2]  += s0.z * w; acc[3]  += s0.w * w;
        acc[4]  += s1.x * w; acc[5]  += s1.y * w; acc[6]  += s1.z * w; acc[7]  += s1.w * w;
        acc[8]  += s2.x * w; acc[9]  += s2.y * w; acc[10] += s2.z * w; acc[11] += s2.w * w;
        acc[12] += s3.x * w; acc[13] += s3.y * w; acc[14] += s3.z * w; acc[15] += s3.w * w;
    }
    float* pp = part_ + (size_t)(kt * CT1 + ct) * 16 * 256;
#pragma unroll
    for (int b = 0; b < 16; b++) pp[b * 256 + tid] = acc[b];
}

// reduce partials + BatchNorm + LeakyReLU in one pass
__global__ void k_credbn(float* __restrict__ hact, const float* __restrict__ part_,
                         const float* __restrict__ bm1, const float* __restrict__ gamma,
                         const float* __restrict__ beta, const float* __restrict__ mean,
                         const float* __restrict__ var) {
    int idx = blockIdx.x * 256 + threadIdx.x;
    if (idx >= BSZ * CLS) return;
    int b = idx / CLS, c = idx % CLS;
    int ct = c >> 8, cl = c & 255;
    float sum = 0.f;
#pragma unroll 8
    for (int kt = 0; kt < KT1; kt++)
        sum += part_[((size_t)(kt * CT1 + ct) * 16 + b) * 256 + cl];
    float t = sum + bm1[c];
    t = gamma[c] * (t - mean[c]) * rsqrtf(var[c] + 1e-5f) + beta[c];
    hact[idx] = t > 0.f ? t : 0.01f * t;
}

// one block per batch row; 128 partials per output
__global__ void k_out(float* __restrict__ outp, const float* __restrict__ hact,
                      const float* __restrict__ Wm2, const float* __restrict__ bm2) {
    int b = blockIdx.x;
    int tid = threadIdx.x;
    int o = tid & 1, part = tid >> 1;   // 2 outputs x 128 partials
    float acc = (part == 0) ? bm2[o] : 0.f;
    for (int k = part; k < CLS; k += 128) acc += hact[b * CLS + k] * Wm2[k * OCH + o];
    unsafeAtomicAdd(&outp[b * OCH + o], acc);
}

extern "C" void kernel_launch(void* const* d_in, const int* in_sizes, int n_in,
                              void* d_out, int out_size, void* d_ws, size_t ws_size,
                              hipStream_t stream) {
    const float* x1  = (const float*)d_in[0];
    const int*   nl  = (const int*)d_in[1];
    const int*   ei1 = (const int*)d_in[2];
    const float* ew1 = (const float*)d_in[3];
    const int*   ba1 = (const int*)d_in[4];
    const float* x2  = (const float*)d_in[5];
    const int*   rl  = (const int*)d_in[6];
    const int*   ei2 = (const int*)d_in[7];
    const float* ew2 = (const float*)d_in[8];
    const int*   ba2 = (const int*)d_in[9];
    const float* W1a = (const float*)d_in[10];
    const float* b1a = (const float*)d_in[11];
    const float* W1b = (const float*)d_in[12];
    const float* b1b = (const float*)d_in[13];
    const float* W2a = (const float*)d_in[14];
    const float* b2a = (const float*)d_in[15];
    const float* W2b = (const float*)d_in[16];
    const float* b2b = (const float*)d_in[17];
    const float* Wm1 = (const float*)d_in[18];
    const float* bm1 = (const float*)d_in[19];
    const float* gam = (const float*)d_in[20];
    const float* bet = (const float*)d_in[21];
    const float* bmn = (const float*)d_in[22];
    const float* bvr = (const float*)d_in[23];
    const float* Wm2 = (const float*)d_in[24];
    const float* bm2 = (const float*)d_in[25];

    float* out  = (float*)d_out;
    float* emb1 = out + 32;               // embedding        (16 x 9472)
    float* emb2 = emb1 + NSEG * HID;      // embedding_roi
    float* esum = emb2 + NSEG * HID;      // embedding + embedding_roi

    // ---- workspace carve ----
    char* p = (char*)d_ws;
    auto carve = [&](size_t nbytes) { char* q = p; p += (nbytes + 255) & ~(size_t)255; return (void*)q; };
    int*    row1    = (int*)   carve((N1 + 1) * 4);
    int2*   edges1  = (int2*)  carve((size_t)E1 * 8);
    float*  dinv1   = (float*) carve(N1 * 4);
    __half* A1h     = (__half*)carve((size_t)N1 * HID * 2);   // fp16 h (gemm out)
    __half* B1h     = (__half*)carve((size_t)N1 * HID * 2);   // fp16 conv out
    int*    nodeid1 = (int*)   carve(N1 * 4);
    int*    segrow1 = (int*)   carve((NSEG + 1) * 4);
    int*    segoff  = (int*)   carve(2 * NSEG * 4);           // [0..NSEG) g1, [NSEG..) g2
    int*    bh      = (int*)   carve((NB1 * BLK1 + 1) * 4);
    int*    obh     = (int*)   carve((NB1 * BLK1 + 1) * 4);
    int*    row2    = (int*)   carve((N2 + 1) * 4);
    int*    off2    = (int*)   carve(N2 * 4);
    int2*   edges2  = (int2*)  carve((size_t)E2 * 8);
    float*  dinv2   = (float*) carve(N2 * 4);
    __half* A2h     = (__half*)carve((size_t)N2 * HID * 2);
    __half* B2h     = (__half*)carve((size_t)N2 * HID * 2);
    int*    nodeid2 = (int*)   carve(N2 * 4);
    int*    segrow2 = (int*)   carve((NSEG + 1) * 4);
    int*    part    = (int*)   carve(256 * 4);
    float*  hact    = (float*) carve(BSZ * CLS * 4);
    uint4*  wf1a    = (uint4*) carve(1024 * 16);              // W fragment buffers
    uint4*  wf1b    = (uint4*) carve(512 * 16);
    uint4*  wf2a    = (uint4*) carve(1024 * 16);
    uint4*  wf2b    = (uint4*) carve(512 * 16);
    int*    segoff1 = segoff;
    int*    segoff2 = segoff + NSEG;
    int2*  tmp1 = (int2*)B1h;   // 16.8 MB aliases B1h (16.8 MB): CSR build done
                                // before conv1's first B1h write
    float* clsp = (float*)B1h;  // 9.7 MB partial slabs alias B1h: dead after pool

    const int* src1 = ei1;
    const int* dst1 = ei1 + E1;
    const int* src2 = ei2;
    const int* dst2 = ei2 + E2;

    hipMemsetAsync(d_out, 0, (size_t)out_size * sizeof(float), stream);

    // ---------------- weight fragment prep (independent; overlaps CSR build) ----
    k_wprep<<<12, 256, 0, stream>>>(wf1a, W1a, wf1b, W1b, wf2a, W2a, wf2b, W2b);

    // ---------------- graph 2 CSR (small; raw weights, pre-shifted src) -------
    hipMemsetAsync(off2, 0, N2 * 4, stream);
    k_hist_dst<<<(E2 + 255) / 256, 256, 0, stream>>>(off2, dst2, E2);
    k_scan_one<<<1, 256, 0, stream>>>(off2, row2, off2, N2, nullptr, nullptr, nullptr, 0);
    k_fill_edges<<<(E2 + 255) / 256, 256, 0, stream>>>(edges2, off2, src2, dst2, ew2, E2);
    k_deg_dinv<<<(N2 + 255) / 256, 256, 0, stream>>>(dinv2, row2, edges2, N2);

    // ---------------- graph 1 CSR: radix-partition build v4 ----------------
    k_p1<<<BLK1, 256, 0, stream>>>(bh, dst1);                    // histogram only
    k_scan1<<<(NB1 * BLK1 + 1023) / 1024, 256, 0, stream>>>(bh, obh, part, NB1 * BLK1);
    k_scan2<<<1, 256, 0, stream>>>(part, (NB1 * BLK1 + 1023) / 1024);
    k_scan3<<<(NB1 * BLK1 + 255) / 256, 256, 0, stream>>>(obh, part, NB1 * BLK1, E1);
    k_p2<<<BLK1, 256, 0, stream>>>(tmp1, obh, src1, dst1, ew1);  // raw-weight sort
    k_p3<<<NB1, 256, 0, stream>>>(edges1, row1, dinv1, tmp1, obh);  // CSR + row1 + dinv

    // ---------------- fused dense pipeline (both graphs per dispatch) ----------------
    k_gemm<INCH, float><<<GEMMB, 256, 0, stream>>>(A1h, x1, wf1a, dinv1, T1,
                                                   A2h, x2, wf2a, dinv2, T2);
    k_conv<<<CW1 + CW2, 256, 0, stream>>>(B1h, A1h, edges1, row1, dinv1, b1a, N1, CW1,
                                          B2h, A2h, edges2, row2, dinv2, b2a, N2, 1);
    k_gemm<HID, __half><<<GEMMB, 256, 0, stream>>>(A1h, B1h, wf1b, nullptr, T1,
                                                   A2h, B2h, wf2b, nullptr, T2);
    k_conv<<<CW1 + CW2, 256, 0, stream>>>(B1h, A1h, edges1, row1, dinv1, b1b, N1, CW1,
                                          B2h, A2h, edges2, row2, dinv2, b2b, N2, 0);

    // ---------------- segment CSR + pool (both graphs) ----------------
    hipMemsetAsync(segoff, 0, 2 * NSEG * 4, stream);
    k_hist_seg2<<<(N1 + N2 + 255) / 256, 256, 0, stream>>>(segoff1, ba1, nl, N1,
                                                           segoff2, ba2, rl, N2);
    k_scan_one<<<2, 256, 0, stream>>>(segoff1, segrow1, segoff1, NSEG,
                                      segoff2, segrow2, segoff2, NSEG);
    k_fill_seg2<<<(N1 + N2 + 255) / 256, 256, 0, stream>>>(nodeid1, segoff1, ba1, nl, N1,
                                                           nodeid2, segoff2, ba2, rl, N2);
    k_pool<<<PW + PW, 256, 0, stream>>>(emb1, B1h, nodeid1, segrow1, PW,
                                        emb2, B2h, nodeid2, segrow2);
    // B1h dead from here; clsp aliases it

    // ---------------- classifier ----------------
    k_cls<<<KT1 * CT1, 256, 0, stream>>>(clsp, emb1, emb2, esum, Wm1);
    k_credbn<<<(BSZ * CLS + 255) / 256, 256, 0, stream>>>(hact, clsp, bm1, gam, bet, bmn, bvr);
    k_out<<<BSZ, 256, 0, stream>>>(out, hact, Wm2, bm2);
}

// Round 10
// 459.367 us; speedup vs baseline: 1.3186x; 1.0745x over previous
//
#include <hip/hip_runtime.h>
#include <hip/hip_fp16.h>

#define N1 131072
#define E1 2097152
#define N2 2368
#define E2 37888
#define NROIS 148
#define BSZ 16
#define HID 64
#define INCH 128
#define NSEG (BSZ*NROIS)      /* 2368 */
#define SDIM (NROIS*HID)      /* 9472 */
#define CLS 1000
#define OCH 2

#define KT1 148               /* k tiles for k_cls */
#define KCC 64                /* k per tile (148*64 = 9472) */
#define CT1 4                 /* col tiles of 256 */
#define SLP 20                /* LDS slab row stride (floats): 80 B, 16B-aligned */

#define NB1 512               /* dst buckets for graph-1 partition */
#define BLK1 512              /* partition blocks */
#define EPB (E1/BLK1)         /* 4096 edges per block */
#define NPB (N1/NB1)          /* 256 nodes per bucket */
#define P3CAP 5120            /* LDS edge stage cap (mean 4096, sd 64: +16 sd) */

#define G2HB ((E2+255)/256)   /* 148 graph2-hist/fill rider blocks */
#define G2DB ((N2+255)/256)   /* 10 graph2 deg_dinv rider blocks */

#define CW1 ((N1+15)/16)      /* 8192 conv blocks graph1 (16 nodes/block) */
#define CW2 ((N2+15)/16)      /* 148 conv blocks graph2 */
#define PW  ((NSEG+15)/16)    /* 148 pool blocks per graph */

#define T1 (N1/16)            /* 8192 mfma row-tiles graph1 */
#define T2 (N2/16)            /* 148 mfma row-tiles graph2 */
#define GEMMB ((T1+T2)/4)     /* 2085 gemm blocks (1 tile/wave, 4 waves/block) */

typedef _Float16 h8 __attribute__((ext_vector_type(8)));
typedef float f4 __attribute__((ext_vector_type(4)));

__device__ __forceinline__ unsigned packh2(float a, float b) {
    return (unsigned)__half_as_ushort(__float2half_rn(a)) |
           ((unsigned)__half_as_ushort(__float2half_rn(b)) << 16);
}

// fp32 acc += (f16 half of hb) * w  -- single VALU op, no unpack
__device__ __forceinline__ void fma_lo(float& a, unsigned hb, float w) {
    asm("v_fma_mix_f32 %0, %1, %2, %0 op_sel:[0,0,0] op_sel_hi:[1,0,0]"
        : "+v"(a) : "v"(hb), "v"(w));
}
__device__ __forceinline__ void fma_hi(float& a, unsigned hb, float w) {
    asm("v_fma_mix_f32 %0, %1, %2, %0 op_sel:[1,0,0] op_sel_hi:[1,0,0]"
        : "+v"(a) : "v"(hb), "v"(w));
}

// ======= dinv factoring =======
// out[d] = dinv[d]*( sum_s ew*(dinv[s]*h[s]) + dinv[d]*h[d] ) + bias
// gemm1 scales rows by dinv (H~ = dinv*h); conv aggregates RAW ew over H~,
// adds H~[d], multiplies by dinv[d], adds bias, relu; conv1 pre-scales its
// output by dinv[d] for the next gemm; conv2 outputs plain.

// ---------------- segment CSR helpers ----------------

__global__ void k_hist_seg2(int* __restrict__ c1, const int* __restrict__ b1,
                            const int* __restrict__ l1, int n1_,
                            int* __restrict__ c2, const int* __restrict__ b2,
                            const int* __restrict__ l2, int n2_) {
    int i = blockIdx.x * 256 + threadIdx.x;
    if (i < n1_) { atomicAdd(&c1[b1[i] * NROIS + l1[i]], 1); return; }
    int j = i - n1_;
    if (j < n2_) atomicAdd(&c2[b2[j] * NROIS + l2[j]], 1);
}

// multi-block exclusive scan (used for the obh bucket histogram)
__global__ void k_scan1(const int* __restrict__ in, int* __restrict__ out,
                        int* __restrict__ part, int n) {
    __shared__ int sh[256];
    int t = threadIdx.x;
    int i0 = blockIdx.x * 1024 + t * 4;
    int v0 = (i0     < n) ? in[i0]     : 0;
    int v1 = (i0 + 1 < n) ? in[i0 + 1] : 0;
    int v2 = (i0 + 2 < n) ? in[i0 + 2] : 0;
    int v3 = (i0 + 3 < n) ? in[i0 + 3] : 0;
    int tot = v0 + v1 + v2 + v3;
    sh[t] = tot; __syncthreads();
    for (int off = 1; off < 256; off <<= 1) {
        int x = 0; if (t >= off) x = sh[t - off];
        __syncthreads();
        if (t >= off) sh[t] += x;
        __syncthreads();
    }
    int excl = sh[t] - tot;
    if (t == 255) part[blockIdx.x] = sh[255];
    if (i0     < n) out[i0]     = excl;
    if (i0 + 1 < n) out[i0 + 1] = excl + v0;
    if (i0 + 2 < n) out[i0 + 2] = excl + v0 + v1;
    if (i0 + 3 < n) out[i0 + 3] = excl + v0 + v1 + v2;
}

// block 0: scans part[cnt]. block 1: single-block exclusive scan of in2[n2]
// -> out2 (+ sentinel) and oo2 (replaces the old standalone graph-2 scan).
__global__ void k_scan2(int* __restrict__ part, int cnt,
                        const int* __restrict__ in2, int* __restrict__ out2,
                        int* __restrict__ oo2, int n2) {
    __shared__ int sh[256];
    __shared__ int carry;
    int t = threadIdx.x;
    if (blockIdx.x == 1) {
        if (t == 0) carry = 0;
        __syncthreads();
        for (int base = 0; base < n2; base += 256) {
            int i = base + t;
            int v = (i < n2) ? in2[i] : 0;
            sh[t] = v; __syncthreads();
            for (int off = 1; off < 256; off <<= 1) {
                int x = 0; if (t >= off) x = sh[t - off];
                __syncthreads();
                if (t >= off) sh[t] += x;
                __syncthreads();
            }
            if (i < n2) {
                int e = carry + sh[t] - v;
                out2[i] = e;
                oo2[i] = e;
            }
            __syncthreads();
            if (t == 255) carry += sh[255];
            __syncthreads();
        }
        if (t == 0) out2[n2] = carry;
        return;
    }
    int v = (t < cnt) ? part[t] : 0;
    sh[t] = v; __syncthreads();
    for (int off = 1; off < 256; off <<= 1) {
        int x = 0; if (t >= off) x = sh[t - off];
        __syncthreads();
        if (t >= off) sh[t] += x;
        __syncthreads();
    }
    if (t < cnt) part[t] = sh[t] - v;
}

__global__ void k_scan3(int* __restrict__ out, const int* __restrict__ part, int n, int total) {
    int i = blockIdx.x * 256 + threadIdx.x;
    if (i < n) out[i] += part[i >> 10];
    if (i == 0) out[n] = total;
}

// single-block exclusive scan; block 0 scans set A, block 1 set B.
__global__ void k_scan_one(const int* __restrict__ in0, int* __restrict__ out0,
                           int* __restrict__ oo0, int n0,
                           const int* __restrict__ in1, int* __restrict__ out1,
                           int* __restrict__ oo1, int n1_) {
    __shared__ int sh[256];
    __shared__ int carry;
    const int* in; int* out; int* oo; int n;
    if (blockIdx.x == 0) { in = in0; out = out0; oo = oo0; n = n0; }
    else { if (!in1) return; in = in1; out = out1; oo = oo1; n = n1_; }
    int t = threadIdx.x;
    if (t == 0) carry = 0;
    __syncthreads();
    for (int base = 0; base < n; base += 256) {
        int i = base + t;
        int v = (i < n) ? in[i] : 0;
        sh[t] = v; __syncthreads();
        for (int off = 1; off < 256; off <<= 1) {
            int x = 0; if (t >= off) x = sh[t - off];
            __syncthreads();
            if (t >= off) sh[t] += x;
            __syncthreads();
        }
        if (i < n) {
            int e = carry + sh[t] - v;
            out[i] = e;
            if (oo) oo[i] = e;
        }
        __syncthreads();
        if (t == 255) carry += sh[255];
        __syncthreads();
    }
    if (t == 0) out[n] = carry;
}

// writes PRE-SHIFTED node ids (i << 7 = byte offset of fp16 row) for pool gathers
__global__ void k_fill_seg2(int* __restrict__ id1, int* __restrict__ o1,
                            const int* __restrict__ b1, const int* __restrict__ l1, int n1_,
                            int* __restrict__ id2, int* __restrict__ o2,
                            const int* __restrict__ b2, const int* __restrict__ l2, int n2_) {
    int i = blockIdx.x * 256 + threadIdx.x;
    if (i < n1_) {
        int pos = atomicAdd(&o1[b1[i] * NROIS + l1[i]], 1);
        id1[pos] = i << 7;
        return;
    }
    int j = i - n1_;
    if (j < n2_) {
        int pos = atomicAdd(&o2[b2[j] * NROIS + l2[j]], 1);
        id2[pos] = j << 7;
    }
}

// ---------------- graph-1 radix-partition CSR build (v5, graph-2 riders) -------
// p1: bucket histogram (+148 rider blocks: graph-2 dst histogram)
// p2: LDS counting sort, RAW weights, coalesced writes (+riders: graph-2 fill)
// p3: per-bucket sort + row1 + dinv1 (+riders: graph-2 deg/dinv)

__global__ __launch_bounds__(256) void k_p1(int* __restrict__ bh, const int* __restrict__ dst,
                                            int* __restrict__ off2, const int* __restrict__ dst2) {
    __shared__ int cnt[NB1];
    int t = threadIdx.x, blk = blockIdx.x;
    if (blk >= BLK1) {                   // graph-2 histogram rider
        int e = (blk - BLK1) * 256 + t;
        if (e < E2) atomicAdd(&off2[dst2[e]], 1);
        return;
    }
    cnt[t] = 0; cnt[t + 256] = 0;
    __syncthreads();
    int base = blk * EPB;
    const int4* d4 = (const int4*)(dst + base);
    for (int i = t; i < EPB / 4; i += 256) {
        int4 d = d4[i];
        atomicAdd(&cnt[d.x >> 8], 1);
        atomicAdd(&cnt[d.y >> 8], 1);
        atomicAdd(&cnt[d.z >> 8], 1);
        atomicAdd(&cnt[d.w >> 8], 1);
    }
    __syncthreads();
    bh[t * BLK1 + blk] = cnt[t];                  // bucket-major
    bh[(t + 256) * BLK1 + blk] = cnt[t + 256];
}

__global__ __launch_bounds__(256) void k_p2(int2* __restrict__ tmp, const int* __restrict__ obh,
                                            const int* __restrict__ src,
                                            const int* __restrict__ dst,
                                            const float* __restrict__ ew,
                                            int2* __restrict__ edges2, int* __restrict__ off2,
                                            const int* __restrict__ src2,
                                            const int* __restrict__ dst2,
                                            const float* __restrict__ ew2) {
    __shared__ int2 stage[EPB];           // 32 KB bucket-sorted edges
    __shared__ unsigned short bkt[EPB];   // 8 KB bucket per slot
    __shared__ int cnt[NB1];
    __shared__ int lofs[NB1];
    __shared__ int gdel[NB1];
    __shared__ int cur[NB1];
    __shared__ int sc[256];
    __shared__ int cbr;
    int t = threadIdx.x, blk = blockIdx.x;
    if (blk >= BLK1) {                   // graph-2 fill rider (off2 = scan copy)
        int e = (blk - BLK1) * 256 + t;
        if (e < E2) {
            int pos = atomicAdd(&off2[dst2[e]], 1);
            edges2[pos] = make_int2(src2[e] << 7, __float_as_int(ew2[e]));
        }
        return;
    }
    cnt[t] = 0; cnt[t + 256] = 0;
    __syncthreads();
    int base = blk * EPB;
    const int4* d4 = (const int4*)(dst + base);
    for (int i = t; i < EPB / 4; i += 256) {
        int4 d = d4[i];
        atomicAdd(&cnt[d.x >> 8], 1);
        atomicAdd(&cnt[d.y >> 8], 1);
        atomicAdd(&cnt[d.z >> 8], 1);
        atomicAdd(&cnt[d.w >> 8], 1);
    }
    __syncthreads();
    // exclusive scan of cnt[512] with 256 threads (2 rounds + carry)
    for (int r = 0; r < 2; r++) {
        int v = cnt[r * 256 + t];
        sc[t] = v; __syncthreads();
        for (int off = 1; off < 256; off <<= 1) {
            int x = 0; if (t >= off) x = sc[t - off];
            __syncthreads();
            if (t >= off) sc[t] += x;
            __syncthreads();
        }
        lofs[r * 256 + t] = (r ? cbr : 0) + sc[t] - v;
        if (t == 255 && r == 0) cbr = sc[255];
        __syncthreads();
    }
    for (int b = t; b < NB1; b += 256) {
        int lo = lofs[b];
        cur[b] = lo;
        gdel[b] = obh[b * BLK1 + blk] - lo;
    }
    __syncthreads();
    for (int i = t; i < EPB; i += 256) {
        int e = base + i;
        int d = dst[e];
        int b = d >> 8;
        int p = atomicAdd(&cur[b], 1);
        stage[p] = make_int2(src[e] | ((d & 255) << 17), __float_as_int(ew[e]));
        bkt[p] = (unsigned short)b;
    }
    __syncthreads();
    // linear write-out: consecutive i -> consecutive addresses per bucket run
    for (int i = t; i < EPB; i += 256)
        tmp[gdel[bkt[i]] + i] = stage[i];
}

__global__ __launch_bounds__(256) void k_p3(int2* __restrict__ edges, int* __restrict__ row1,
                                            float* __restrict__ dinv1,
                                            const int2* __restrict__ tmp,
                                            const int* __restrict__ obh,
                                            float* __restrict__ dinv2,
                                            const int* __restrict__ row2,
                                            const int2* __restrict__ edges2, int n2_) {
    __shared__ int2 stage[P3CAP];         // 40 KB
    __shared__ int h[NPB];
    __shared__ float ws[NPB];
    __shared__ int sc[256];
    __shared__ int cur[NPB];
    int t = threadIdx.x, b = blockIdx.x;
    if (b >= NB1) {                      // graph-2 deg/dinv rider
        int d = (b - NB1) * 256 + t;
        if (d < n2_) {
            int a = row2[d], e_ = row2[d + 1];
            float s = 1.0f;
            for (int i = a; i < e_; i++) s += __int_as_float(edges2[i].y);
            dinv2[d] = rsqrtf(s);
        }
        return;
    }
    h[t] = 0; ws[t] = 0.f;
    __syncthreads();
    int A = obh[b * BLK1];
    int Eend = (b == NB1 - 1) ? E1 : obh[(b + 1) * BLK1];
    int len = Eend - A;
    for (int j = t; j < len; j += 256) {
        int2 ed = tmp[A + j];
        if (j < P3CAP) stage[j] = ed;     // overflow (statistically ~never) re-read below
        int dl = (ed.x >> 17) & 255;
        atomicAdd(&h[dl], 1);
        atomicAdd(&ws[dl], __int_as_float(ed.y));
    }
    __syncthreads();
    int cnt_ = h[t];
    sc[t] = cnt_; __syncthreads();
    for (int off = 1; off < 256; off <<= 1) {
        int x = 0; if (t >= off) x = sc[t - off];
        __syncthreads();
        if (t >= off) sc[t] += x;
        __syncthreads();
    }
    int excl = sc[t] - cnt_;
    row1[b * NPB + t] = A + excl;
    dinv1[b * NPB + t] = rsqrtf(1.f + ws[t]);
    cur[t] = excl;
    if (b == NB1 - 1 && t == 255) row1[N1] = E1;
    __syncthreads();
    for (int j = t; j < len; j += 256) {
        int2 ed = (j < P3CAP) ? stage[j] : tmp[A + j];
        int dl = (ed.x >> 17) & 255;
        int s = ed.x & 0x1FFFF;
        int p = atomicAdd(&cur[dl], 1);
        edges[A + p] = make_int2(s << 7, ed.y);   // raw weight; region-local write
    }
}

// ---------------- MFMA gemm ----------------

__device__ __forceinline__ void wfrag(uint4* __restrict__ o, const float* __restrict__ W,
                                      int KCH, int idx) {
    int lane = idx & 63;
    int rest = idx >> 6;
    int ch = rest % KCH;
    int ct = rest / KCH;
    int kr = ch * 32 + ((lane >> 4) * 8);
    int col = ct * 16 + (lane & 15);
    const float* wp = W + (size_t)kr * 64 + col;
    o[idx] = make_uint4(packh2(wp[0],   wp[64]),
                        packh2(wp[128], wp[192]),
                        packh2(wp[256], wp[320]),
                        packh2(wp[384], wp[448]));
}

// also zeroes out[0..31], off2, segoff (absorbs the 3 memsets)
__global__ void k_wprep(uint4* __restrict__ wf1a, const float* __restrict__ W1a,
                        uint4* __restrict__ wf1b, const float* __restrict__ W1b,
                        uint4* __restrict__ wf2a, const float* __restrict__ W2a,
                        uint4* __restrict__ wf2b, const float* __restrict__ W2b,
                        float* __restrict__ outz, int* __restrict__ off2z,
                        int* __restrict__ segoffz) {
    int idx = blockIdx.x * 256 + threadIdx.x;
    if      (idx < 1024) wfrag(wf1a, W1a, 4, idx);
    else if (idx < 1536) wfrag(wf1b, W1b, 2, idx - 1024);
    else if (idx < 2560) wfrag(wf2a, W2a, 4, idx - 1536);
    else if (idx < 3072) wfrag(wf2b, W2b, 2, idx - 2560);
    else if (idx < 3104) outz[idx - 3072] = 0.f;
    else if (idx < 3104 + N2) off2z[idx - 3104] = 0;
    else if (idx < 3104 + N2 + 2 * NSEG) segoffz[idx - 3104 - N2] = 0;
}

__device__ __forceinline__ h8 loadA(const float* p) {
    float4 a = *(const float4*)p;
    float4 b = *(const float4*)(p + 4);
    union { h8 v; __half h[8]; } u;
    u.h[0] = __float2half_rn(a.x); u.h[1] = __float2half_rn(a.y);
    u.h[2] = __float2half_rn(a.z); u.h[3] = __float2half_rn(a.w);
    u.h[4] = __float2half_rn(b.x); u.h[5] = __float2half_rn(b.y);
    u.h[6] = __float2half_rn(b.z); u.h[7] = __float2half_rn(b.w);
    return u.v;
}
__device__ __forceinline__ h8 loadA(const __half* p) {
    union { h8 v; uint4 u; } u;
    u.u = *(const uint4*)p;
    return u.v;
}

template <int K, typename T>
__global__ __launch_bounds__(256) void k_gemm(__half* __restrict__ out1, const T* __restrict__ x1,
                                              const uint4* __restrict__ wfa,
                                              const float* __restrict__ dva, int t1,
                                              __half* __restrict__ out2, const T* __restrict__ x2,
                                              const uint4* __restrict__ wfb,
                                              const float* __restrict__ dvb, int t2) {
    constexpr int KCH = K / 32;
    int wid = blockIdx.x * 4 + (threadIdx.x >> 6);
    int lane = threadIdx.x & 63;
    __half* out; const T* x; const uint4* wf; const float* dv; int row0;
    if (wid < t1) { out = out1; x = x1; wf = wfa; dv = dva; row0 = wid * 16; }
    else {
        int w2 = wid - t1;
        if (w2 >= t2) return;
        out = out2; x = x2; wf = wfb; dv = dvb; row0 = w2 * 16;
    }
    int lrow = lane & 15, lg = lane >> 4;

    h8 bf[4][KCH];
#pragma unroll
    for (int ct = 0; ct < 4; ct++)
#pragma unroll
        for (int ch = 0; ch < KCH; ch++) {
            union { h8 v; uint4 u; } u;
            u.u = wf[(ct * KCH + ch) * 64 + lane];
            bf[ct][ch] = u.v;
        }

    const T* xr = x + (size_t)(row0 + lrow) * K + lg * 8;
    h8 af[KCH];
#pragma unroll
    for (int ch = 0; ch < KCH; ch++) af[ch] = loadA(xr + ch * 32);

    f4 acc[4];
#pragma unroll
    for (int ct = 0; ct < 4; ct++) acc[ct] = (f4){0.f, 0.f, 0.f, 0.f};
#pragma unroll
    for (int ch = 0; ch < KCH; ch++)
#pragma unroll
        for (int ct = 0; ct < 4; ct++)
            acc[ct] = __builtin_amdgcn_mfma_f32_16x16x32_f16(af[ch], bf[ct][ch], acc[ct], 0, 0, 0);

    float scs[4] = {1.f, 1.f, 1.f, 1.f};
    if (dv) {
#pragma unroll
        for (int r = 0; r < 4; r++) scs[r] = dv[row0 + lg * 4 + r];
    }
#pragma unroll
    for (int ct = 0; ct < 4; ct++)
#pragma unroll
        for (int r = 0; r < 4; r++)
            out[(size_t)(row0 + lg * 4 + r) * 64 + ct * 16 + lrow] =
                __float2half_rn(acc[ct][r] * scs[r]);
}

// ---------------- conv / pool (4 nodes/wave; 2-step unrolled gathers) ----------------
__device__ __forceinline__ void conv_wave(__half* __restrict__ out, const __half* __restrict__ h,
                                          const int2* __restrict__ edges,
                                          const int* __restrict__ row,
                                          const float* __restrict__ dinv,
                                          const float* __restrict__ bias,
                                          int d0, int n, int lane, int presc) {
    int g  = lane >> 4;           // node slot 0..3
    int fl = lane & 15;
    int eh = fl >> 3;             // edge half 0/1
    int f8 = fl & 7;              // feature octet
    int d  = d0 + g;
    bool vn = d < n;
    int a = 0, b = 0;
    if (vn) { a = row[d]; b = row[d + 1]; }
    const char* hb = (const char*)h + f8 * 16;
    float acc[8] = {0.f,0.f,0.f,0.f,0.f,0.f,0.f,0.f};

    for (int base = a; base < b; base += 16) {
        int sv = 0, wv = 0;       // zero-pad: w=0 kills invalid contributions
        if (base + fl < b) { int2 e = edges[base + fl]; sv = e.x; wv = e.y; }
        int mm = b - base; if (mm > 16) mm = 16;
        int steps = (mm + 1) >> 1;
        int idx = (g << 4) + eh;
        int t = 0;
        for (; t + 2 <= steps; t += 2) {          // 2 gathers in flight per group
            int   s0 = __shfl(sv, idx + (t << 1));
            float w0 = __int_as_float(__shfl(wv, idx + (t << 1)));
            int   s1 = __shfl(sv, idx + (t << 1) + 2);
            float w1 = __int_as_float(__shfl(wv, idx + (t << 1) + 2));
            uint4 h0 = *(const uint4*)(hb + (unsigned)s0);
            uint4 h1 = *(const uint4*)(hb + (unsigned)s1);
            fma_lo(acc[0], h0.x, w0); fma_hi(acc[1], h0.x, w0);
            fma_lo(acc[2], h0.y, w0); fma_hi(acc[3], h0.y, w0);
            fma_lo(acc[4], h0.z, w0); fma_hi(acc[5], h0.z, w0);
            fma_lo(acc[6], h0.w, w0); fma_hi(acc[7], h0.w, w0);
            fma_lo(acc[0], h1.x, w1); fma_hi(acc[1], h1.x, w1);
            fma_lo(acc[2], h1.y, w1); fma_hi(acc[3], h1.y, w1);
            fma_lo(acc[4], h1.z, w1); fma_hi(acc[5], h1.z, w1);
            fma_lo(acc[6], h1.w, w1); fma_hi(acc[7], h1.w, w1);
        }
        if (t < steps) {
            int   s = __shfl(sv, idx + (t << 1));
            float w = __int_as_float(__shfl(wv, idx + (t << 1)));
            uint4 hv = *(const uint4*)(hb + (unsigned)s);
            fma_lo(acc[0], hv.x, w); fma_hi(acc[1], hv.x, w);
            fma_lo(acc[2], hv.y, w); fma_hi(acc[3], hv.y, w);
            fma_lo(acc[4], hv.z, w); fma_hi(acc[5], hv.z, w);
            fma_lo(acc[6], hv.w, w); fma_hi(acc[7], hv.w, w);
        }
    }
    float r[8];
#pragma unroll
    for (int f = 0; f < 8; f++) r[f] = acc[f] + __shfl_xor(acc[f], 8);
    if (vn && eh == 0) {
        float di = dinv[d];
        uint4 hd = *(const uint4*)(hb + ((unsigned)d << 7));
        fma_lo(r[0], hd.x, 1.f); fma_hi(r[1], hd.x, 1.f);
        fma_lo(r[2], hd.y, 1.f); fma_hi(r[3], hd.y, 1.f);
        fma_lo(r[4], hd.z, 1.f); fma_hi(r[5], hd.z, 1.f);
        fma_lo(r[6], hd.w, 1.f); fma_hi(r[7], hd.w, 1.f);
        float4 b0 = *(const float4*)(bias + f8 * 8);
        float4 b1 = *(const float4*)(bias + f8 * 8 + 4);
        float osc = presc ? di : 1.f;
        float o0 = fmaxf(di * r[0] + b0.x, 0.f) * osc;
        float o1 = fmaxf(di * r[1] + b0.y, 0.f) * osc;
        float o2 = fmaxf(di * r[2] + b0.z, 0.f) * osc;
        float o3 = fmaxf(di * r[3] + b0.w, 0.f) * osc;
        float o4 = fmaxf(di * r[4] + b1.x, 0.f) * osc;
        float o5 = fmaxf(di * r[5] + b1.y, 0.f) * osc;
        float o6 = fmaxf(di * r[6] + b1.z, 0.f) * osc;
        float o7 = fmaxf(di * r[7] + b1.w, 0.f) * osc;
        uint4 ov;
        ov.x = packh2(o0, o1);
        ov.y = packh2(o2, o3);
        ov.z = packh2(o4, o5);
        ov.w = packh2(o6, o7);
        *(uint4*)(out + (size_t)d * HID + f8 * 8) = ov;
    }
}

__global__ __launch_bounds__(256) void k_conv(__half* __restrict__ o1, const __half* __restrict__ h1,
                                              const int2* __restrict__ e1, const int* __restrict__ r1,
                                              const float* __restrict__ dv1, const float* __restrict__ bi1,
                                              int n1_, int nb1_,
                                              __half* __restrict__ o2, const __half* __restrict__ h2,
                                              const int2* __restrict__ e2, const int* __restrict__ r2,
                                              const float* __restrict__ dv2, const float* __restrict__ bi2,
                                              int n2_, int presc) {
    int blk = blockIdx.x;
    int lane = threadIdx.x & 63;
    int wv = threadIdx.x >> 6;
    if (blk < nb1_) conv_wave(o1, h1, e1, r1, dv1, bi1, blk * 16 + wv * 4, n1_, lane, presc);
    else            conv_wave(o2, h2, e2, r2, dv2, bi2, (blk - nb1_) * 16 + wv * 4, n2_, lane, presc);
}

// segment-mean pool, same wave structure + 2-step unroll.
__device__ __forceinline__ void pool_wave(float* __restrict__ emb, const __half* __restrict__ h,
                                          const int* __restrict__ nodeid,
                                          const int* __restrict__ segrow, int s0, int lane) {
    int g  = lane >> 4;
    int fl = lane & 15;
    int eh = fl >> 3;
    int f8 = fl & 7;
    int s  = s0 + g;
    bool vs = s < NSEG;
    int a = 0, b = 0;
    if (vs) { a = segrow[s]; b = segrow[s + 1]; }
    const char* hb = (const char*)h + f8 * 16;
    float acc[8] = {0.f,0.f,0.f,0.f,0.f,0.f,0.f,0.f};

    for (int base = a; base < b; base += 16) {
        int sv = 0, wv = 0;
        if (base + fl < b) { sv = nodeid[base + fl]; wv = 0x3f800000; }
        int mm = b - base; if (mm > 16) mm = 16;
        int steps = (mm + 1) >> 1;
        int idx = (g << 4) + eh;
        int t = 0;
        for (; t + 2 <= steps; t += 2) {
            int   q0 = __shfl(sv, idx + (t << 1));
            float w0 = __int_as_float(__shfl(wv, idx + (t << 1)));
            int   q1 = __shfl(sv, idx + (t << 1) + 2);
            float w1 = __int_as_float(__shfl(wv, idx + (t << 1) + 2));
            uint4 h0 = *(const uint4*)(hb + (unsigned)q0);
            uint4 h1 = *(const uint4*)(hb + (unsigned)q1);
            fma_lo(acc[0], h0.x, w0); fma_hi(acc[1], h0.x, w0);
            fma_lo(acc[2], h0.y, w0); fma_hi(acc[3], h0.y, w0);
            fma_lo(acc[4], h0.z, w0); fma_hi(acc[5], h0.z, w0);
            fma_lo(acc[6], h0.w, w0); fma_hi(acc[7], h0.w, w0);
            fma_lo(acc[0], h1.x, w1); fma_hi(acc[1], h1.x, w1);
            fma_lo(acc[2], h1.y, w1); fma_hi(acc[3], h1.y, w1);
            fma_lo(acc[4], h1.z, w1); fma_hi(acc[5], h1.z, w1);
            fma_lo(acc[6], h1.w, w1); fma_hi(acc[7], h1.w, w1);
        }
        if (t < steps) {
            int   q = __shfl(sv, idx + (t << 1));
            float w = __int_as_float(__shfl(wv, idx + (t << 1)));
            uint4 hv = *(const uint4*)(hb + (unsigned)q);
            fma_lo(acc[0], hv.x, w); fma_hi(acc[1], hv.x, w);
            fma_lo(acc[2], hv.y, w); fma_hi(acc[3], hv.y, w);
            fma_lo(acc[4], hv.z, w); fma_hi(acc[5], hv.z, w);
            fma_lo(acc[6], hv.w, w); fma_hi(acc[7], hv.w, w);
        }
    }
    float r[8];
#pragma unroll
    for (int f = 0; f < 8; f++) r[f] = acc[f] + __shfl_xor(acc[f], 8);
    if (vs && eh == 0) {
        float inv = 1.0f / fmaxf((float)(b - a), 1.0f);
        float4 lo = make_float4(r[0] * inv, r[1] * inv, r[2] * inv, r[3] * inv);
        float4 hi = make_float4(r[4] * inv, r[5] * inv, r[6] * inv, r[7] * inv);
        *(float4*)(emb + (size_t)s * HID + f8 * 8)     = lo;
        *(float4*)(emb + (size_t)s * HID + f8 * 8 + 4) = hi;
    }
}

__global__ __launch_bounds__(256) void k_pool(float* __restrict__ em1, const __half* __restrict__ h1,
                                              const int* __restrict__ id1, const int* __restrict__ sr1,
                                              int nbs,
                                              float* __restrict__ em2, const __half* __restrict__ h2,
                                              const int* __restrict__ id2, const int* __restrict__ sr2) {
    int blk = blockIdx.x;
    int lane = threadIdx.x & 63;
    int wv = threadIdx.x >> 6;
    if (blk < nbs) pool_wave(em1, h1, id1, sr1, blk * 16 + wv * 4, lane);
    else           pool_wave(em2, h2, id2, sr2, (blk - nbs) * 16 + wv * 4, lane);
}

// ---------------- classifier ----------------

__global__ __launch_bounds__(256) void k_cls(float* __restrict__ part_,
                                             const float* __restrict__ e1,
                                             const float* __restrict__ e2,
                                             float* __restrict__ esum,
                                             const float* __restrict__ Wm1) {
    __shared__ float sl[KCC * SLP];     // [kk][b], row stride SLP=20 floats
    int tid = threadIdx.x;
    int kt = blockIdx.x >> 2, ct = blockIdx.x & 3;
    int k0 = kt * KCC;
    bool wr = (ct == 0);
    for (int i = tid; i < KCC * 16; i += 256) {
        int kk = i & (KCC - 1), b = i >> 6;        // coalesced over kk
        int idx = b * SDIM + k0 + kk;
        float v = e1[idx] + e2[idx];
        sl[kk * SLP + b] = v;
        if (wr) esum[idx] = v;
    }
    __syncthreads();
    int c = ct * 256 + tid;
    bool active = c < CLS;
    const float* wp = Wm1 + (size_t)k0 * CLS + c;
    float wv[KCC];
#pragma unroll
    for (int kk = 0; kk < KCC; kk++)
        wv[kk] = active ? wp[(size_t)kk * CLS] : 0.f;   // 64 independent loads in flight
    float acc[16];
#pragma unroll
    for (int b = 0; b < 16; b++) acc[b] = 0.f;
#pragma unroll
    for (int kk = 0; kk < KCC; kk++) {
        float w = wv[kk];
        float4 s0 = *(const float4*)(&sl[kk * SLP + 0]);
        float4 s1 = *(const float4*)(&sl[kk * SLP + 4]);
        float4 s2 = *(const float4*)(&sl[kk * SLP + 8]);
        float4 s3 = *(const float4*)(&sl[kk * SLP + 12]);
        acc[0]  += s0.x * w; acc[1]  += s0.y * w; acc[2]  += s0.z * w; acc[3]  += s0.w * w;
        acc[4]  += s1.x * w; acc[5]  += s1.y * w; acc[6]  += s1.z * w; acc[7]  += s1.w * w;
        acc[8]  += s2.x * w; acc[9]  += s2.y * w; acc[10] += s2.z * w; acc[11] += s2.w * w;
        acc[12] += s3.x * w; acc[13] += s3.y * w; acc[14] += s3.z * w; acc[15] += s3.w * w;
    }
    float* pp = part_ + (size_t)(kt * CT1 + ct) * 16 * 256;
#pragma unroll
    for (int b = 0; b < 16; b++) pp[b * 256 + tid] = acc[b];
}

// reduce partials + BatchNorm + LeakyReLU + final 1000x2 matvec, fused.
// Per-thread product, wave-reduce (uniform-b waves) or per-lane atomic
// (the ~16 batch-boundary waves); out[] zero-initialized by k_wprep.
__global__ void k_credbn(float* __restrict__ outp, const float* __restrict__ part_,
                         const float* __restrict__ bm1, const float* __restrict__ gamma,
                         const float* __restrict__ beta, const float* __restrict__ mean,
                         const float* __restrict__ var, const float* __restrict__ Wm2,
                         const float* __restrict__ bm2) {
    int idx = blockIdx.x * 256 + threadIdx.x;
    float p0 = 0.f, p1 = 0.f;
    int b = 0;
    if (idx < BSZ * CLS) {
        b = idx / CLS;
        int c = idx % CLS;
        int ct = c >> 8, cl = c & 255;
        float sum = 0.f;
#pragma unroll 8
        for (int kt = 0; kt < KT1; kt++)
            sum += part_[((size_t)(kt * CT1 + ct) * 16 + b) * 256 + cl];
        float t = sum + bm1[c];
        t = gamma[c] * (t - mean[c]) * rsqrtf(var[c] + 1e-5f) + beta[c];
        t = t > 0.f ? t : 0.01f * t;
        p0 = t * Wm2[c * OCH];
        p1 = t * Wm2[c * OCH + 1];
        if (c == 0) { p0 += bm2[0]; p1 += bm2[1]; }
    }
    int b0 = __shfl(b, 0), b63 = __shfl(b, 63);
    if (b0 == b63) {                       // wave-uniform batch row (common case)
        float s0 = p0, s1 = p1;
#pragma unroll
        for (int off = 32; off >= 1; off >>= 1) {
            s0 += __shfl_down(s0, off);
            s1 += __shfl_down(s1, off);
        }
        if ((threadIdx.x & 63) == 0 && idx < BSZ * CLS) {
            unsafeAtomicAdd(&outp[b * OCH],     s0);
            unsafeAtomicAdd(&outp[b * OCH + 1], s1);
        }
    } else if (idx < BSZ * CLS) {          // boundary wave: per-lane atomics
        unsafeAtomicAdd(&outp[b * OCH],     p0);
        unsafeAtomicAdd(&outp[b * OCH + 1], p1);
    }
}

extern "C" void kernel_launch(void* const* d_in, const int* in_sizes, int n_in,
                              void* d_out, int out_size, void* d_ws, size_t ws_size,
                              hipStream_t stream) {
    const float* x1  = (const float*)d_in[0];
    const int*   nl  = (const int*)d_in[1];
    const int*   ei1 = (const int*)d_in[2];
    const float* ew1 = (const float*)d_in[3];
    const int*   ba1 = (const int*)d_in[4];
    const float* x2  = (const float*)d_in[5];
    const int*   rl  = (const int*)d_in[6];
    const int*   ei2 = (const int*)d_in[7];
    const float* ew2 = (const float*)d_in[8];
    const int*   ba2 = (const int*)d_in[9];
    const float* W1a = (const float*)d_in[10];
    const float* b1a = (const float*)d_in[11];
    const float* W1b = (const float*)d_in[12];
    const float* b1b = (const float*)d_in[13];
    const float* W2a = (const float*)d_in[14];
    const float* b2a = (const float*)d_in[15];
    const float* W2b = (const float*)d_in[16];
    const float* b2b = (const float*)d_in[17];
    const float* Wm1 = (const float*)d_in[18];
    const float* bm1 = (const float*)d_in[19];
    const float* gam = (const float*)d_in[20];
    const float* bet = (const float*)d_in[21];
    const float* bmn = (const float*)d_in[22];
    const float* bvr = (const float*)d_in[23];
    const float* Wm2 = (const float*)d_in[24];
    const float* bm2 = (const float*)d_in[25];

    float* out  = (float*)d_out;
    float* emb1 = out + 32;               // embedding        (16 x 9472)
    float* emb2 = emb1 + NSEG * HID;      // embedding_roi
    float* esum = emb2 + NSEG * HID;      // embedding + embedding_roi

    // ---- workspace carve ----
    char* p = (char*)d_ws;
    auto carve = [&](size_t nbytes) { char* q = p; p += (nbytes + 255) & ~(size_t)255; return (void*)q; };
    int*    row1    = (int*)   carve((N1 + 1) * 4);
    int2*   edges1  = (int2*)  carve((size_t)E1 * 8);
    float*  dinv1   = (float*) carve(N1 * 4);
    __half* A1h     = (__half*)carve((size_t)N1 * HID * 2);   // fp16 h (gemm out)
    __half* B1h     = (__half*)carve((size_t)N1 * HID * 2);   // fp16 conv out
    int*    nodeid1 = (int*)   carve(N1 * 4);
    int*    segrow1 = (int*)   carve((NSEG + 1) * 4);
    int*    segoff  = (int*)   carve(2 * NSEG * 4);           // [0..NSEG) g1, [NSEG..) g2
    int*    bh      = (int*)   carve((NB1 * BLK1 + 1) * 4);
    int*    obh     = (int*)   carve((NB1 * BLK1 + 1) * 4);
    int*    row2    = (int*)   carve((N2 + 1) * 4);
    int*    off2    = (int*)   carve(N2 * 4);
    int2*   edges2  = (int2*)  carve((size_t)E2 * 8);
    float*  dinv2   = (float*) carve(N2 * 4);
    __half* A2h     = (__half*)carve((size_t)N2 * HID * 2);
    __half* B2h     = (__half*)carve((size_t)N2 * HID * 2);
    int*    nodeid2 = (int*)   carve(N2 * 4);
    int*    segrow2 = (int*)   carve((NSEG + 1) * 4);
    int*    part    = (int*)   carve(256 * 4);
    uint4*  wf1a    = (uint4*) carve(1024 * 16);              // W fragment buffers
    uint4*  wf1b    = (uint4*) carve(512 * 16);
    uint4*  wf2a    = (uint4*) carve(1024 * 16);
    uint4*  wf2b    = (uint4*) carve(512 * 16);
    int*    segoff1 = segoff;
    int*    segoff2 = segoff + NSEG;
    int2*  tmp1 = (int2*)B1h;   // 16.8 MB aliases B1h (16.8 MB): CSR build done
                                // before conv1's first B1h write
    float* clsp = (float*)B1h;  // 9.7 MB partial slabs alias B1h: dead after pool

    const int* src1 = ei1;
    const int* dst1 = ei1 + E1;
    const int* src2 = ei2;
    const int* dst2 = ei2 + E2;

    // 1. wprep: W fragments + zero out[0..31], off2, segoff (absorbs 3 memsets)
    k_wprep<<<41, 256, 0, stream>>>(wf1a, W1a, wf1b, W1b, wf2a, W2a, wf2b, W2b,
                                    out, off2, segoff);

    // 2-7. CSR builds (graph-2 work rides as extra blocks)
    k_p1<<<BLK1 + G2HB, 256, 0, stream>>>(bh, dst1, off2, dst2);
    k_scan1<<<(NB1 * BLK1 + 1023) / 1024, 256, 0, stream>>>(bh, obh, part, NB1 * BLK1);
    k_scan2<<<2, 256, 0, stream>>>(part, (NB1 * BLK1 + 1023) / 1024,
                                   off2, row2, off2, N2);
    k_scan3<<<(NB1 * BLK1 + 255) / 256, 256, 0, stream>>>(obh, part, NB1 * BLK1, E1);
    k_p2<<<BLK1 + G2HB, 256, 0, stream>>>(tmp1, obh, src1, dst1, ew1,
                                          edges2, off2, src2, dst2, ew2);
    k_p3<<<NB1 + G2DB, 256, 0, stream>>>(edges1, row1, dinv1, tmp1, obh,
                                         dinv2, row2, edges2, N2);

    // 8-11. fused dense pipeline (both graphs per dispatch)
    k_gemm<INCH, float><<<GEMMB, 256, 0, stream>>>(A1h, x1, wf1a, dinv1, T1,
                                                   A2h, x2, wf2a, dinv2, T2);
    k_conv<<<CW1 + CW2, 256, 0, stream>>>(B1h, A1h, edges1, row1, dinv1, b1a, N1, CW1,
                                          B2h, A2h, edges2, row2, dinv2, b2a, N2, 1);
    k_gemm<HID, __half><<<GEMMB, 256, 0, stream>>>(A1h, B1h, wf1b, nullptr, T1,
                                                   A2h, B2h, wf2b, nullptr, T2);
    k_conv<<<CW1 + CW2, 256, 0, stream>>>(B1h, A1h, edges1, row1, dinv1, b1b, N1, CW1,
                                          B2h, A2h, edges2, row2, dinv2, b2b, N2, 0);

    // 12-15. segment CSR + pool (both graphs)
    k_hist_seg2<<<(N1 + N2 + 255) / 256, 256, 0, stream>>>(segoff1, ba1, nl, N1,
                                                           segoff2, ba2, rl, N2);
    k_scan_one<<<2, 256, 0, stream>>>(segoff1, segrow1, segoff1, NSEG,
                                      segoff2, segrow2, segoff2, NSEG);
    k_fill_seg2<<<(N1 + N2 + 255) / 256, 256, 0, stream>>>(nodeid1, segoff1, ba1, nl, N1,
                                                           nodeid2, segoff2, ba2, rl, N2);
    k_pool<<<PW + PW, 256, 0, stream>>>(emb1, B1h, nodeid1, segrow1, PW,
                                        emb2, B2h, nodeid2, segrow2);
    // B1h dead from here; clsp aliases it

    // 16-17. classifier (credbn + final matvec fused)
    k_cls<<<KT1 * CT1, 256, 0, stream>>>(clsp, emb1, emb2, esum, Wm1);
    k_credbn<<<(BSZ * CLS + 255) / 256, 256, 0, stream>>>(out, clsp, bm1, gam, bet,
                                                          bmn, bvr, Wm2, bm2);
}